// Round 3
// baseline (1041.674 us; speedup 1.0000x reference)
//
#include <hip/hip_runtime.h>

typedef __bf16 bf16_t;
typedef bf16_t bf16x8 __attribute__((ext_vector_type(8)));
typedef bf16_t bf16x4v __attribute__((ext_vector_type(4)));
typedef float f32x4 __attribute__((ext_vector_type(4)));

// B=2, S=2048, HID=2048, H=16, Q_LORA=1536, KV_LORA=512, D_NOPE=128, D_ROPE=64, D_V=128, D_QK=192
static constexpr float QSCALE = 0.07216878364870323f * 1.44269504088896341f; // 192^-0.5 * log2(e)

#define AS1 __attribute__((address_space(1)))
#define AS3 __attribute__((address_space(3)))
__device__ __forceinline__ void g2lds16(const void* g, void* l) {
  __builtin_amdgcn_global_load_lds((const AS1 void*)g, (AS3 void*)l, 16, 0, 0);
}

// ---------------- cast fp32 -> bf16 (8 elems/thread) ----------------
__global__ void k_cast_bf16(const float* __restrict__ in, bf16_t* __restrict__ out, int n8) {
  int i = blockIdx.x * 256 + threadIdx.x;
  if (i >= n8) return;
  const float4* p = (const float4*)in + (size_t)i * 2;
  float4 a = p[0], b = p[1];
  bf16x8 o = {(bf16_t)a.x, (bf16_t)a.y, (bf16_t)a.z, (bf16_t)a.w,
              (bf16_t)b.x, (bf16_t)b.y, (bf16_t)b.z, (bf16_t)b.w};
  ((bf16x8*)out)[i] = o;
}

// ---------------- generic bf16 GEMM: C(MxN) = A(MxK) * Bt(NxK)^T ----------------
// 128x128 tile, BK=32, 4 waves. global_load_lds width=16 staging into linear [128][32].
// Per wave: 2 A-issues + 2 B-issues of 16 rows each (lane l -> row base+(l>>2), col (l&3)*8).
__global__ __launch_bounds__(256) void k_gemm(
    const bf16_t* __restrict__ A, const bf16_t* __restrict__ Bt,
    float* __restrict__ C, int M, int N, int K) {
  __shared__ __align__(16) bf16_t As[128][32];
  __shared__ __align__(16) bf16_t Bs[128][32];
  const int tid = threadIdx.x;
  const int lane = tid & 63, wid = tid >> 6;
  const int wr = wid >> 1, wc = wid & 1;
  const int lr = lane & 15, lk = lane >> 4;
  const int bm = blockIdx.y * 128, bn = blockIdx.x * 128;
  f32x4 acc[4][4] = {};
  const int srow = wid * 16 + (lane >> 2);
  const int scol = (lane & 3) * 8;
  const bf16_t* a0 = A + (size_t)(bm + srow) * K + scol;
  const bf16_t* a1 = A + (size_t)(bm + 64 + srow) * K + scol;
  const bf16_t* b0 = Bt + (size_t)(bn + srow) * K + scol;       // OOB rows (N=576 case) read
  const bf16_t* b1 = Bt + (size_t)(bn + 64 + srow) * K + scol;  // adjacent ws; masked at store
  bf16_t* lA0 = &As[wid * 16][0];
  bf16_t* lA1 = &As[64 + wid * 16][0];
  bf16_t* lB0 = &Bs[wid * 16][0];
  bf16_t* lB1 = &Bs[64 + wid * 16][0];
  for (int kt = 0; kt < K; kt += 32) {
    g2lds16(a0 + kt, lA0);
    g2lds16(a1 + kt, lA1);
    g2lds16(b0 + kt, lB0);
    g2lds16(b1 + kt, lB1);
    __syncthreads();
    bf16x8 af[4], bff[4];
#pragma unroll
    for (int i = 0; i < 4; i++)
      af[i] = *(const bf16x8*)(&As[wr * 64 + i * 16 + lr][lk * 8]);
#pragma unroll
    for (int j = 0; j < 4; j++)
      bff[j] = *(const bf16x8*)(&Bs[wc * 64 + j * 16 + lr][lk * 8]);
#pragma unroll
    for (int i = 0; i < 4; i++)
#pragma unroll
      for (int j = 0; j < 4; j++)
        acc[i][j] = __builtin_amdgcn_mfma_f32_16x16x32_bf16(af[i], bff[j], acc[i][j], 0, 0, 0);
    __syncthreads();
  }
  const int crow = bm + wr * 64 + lk * 4;
  const int ccol = bn + wc * 64 + lr;
#pragma unroll
  for (int i = 0; i < 4; i++)
#pragma unroll
    for (int j = 0; j < 4; j++) {
      int col = ccol + j * 16;
      if (col < N) {
#pragma unroll
        for (int r = 0; r < 4; r++)
          C[(size_t)(crow + i * 16 + r) * N + col] = acc[i][j][r];
      }
    }
}

// ---------------- RMSNorm over 1536 (q_a) -> bf16 ----------------
__global__ __launch_bounds__(256) void k_rms_q(const float* __restrict__ in,
                                               const float* __restrict__ w,
                                               bf16_t* __restrict__ out) {
  int row = blockIdx.x;
  const float4* x4 = (const float4*)(in + (size_t)row * 1536);
  float ss = 0.f;
  for (int i = threadIdx.x; i < 384; i += 256) {
    float4 v = x4[i];
    ss += v.x * v.x + v.y * v.y + v.z * v.z + v.w * v.w;
  }
  for (int m = 32; m; m >>= 1) ss += __shfl_xor(ss, m);
  __shared__ float parts[4];
  if ((threadIdx.x & 63) == 0) parts[threadIdx.x >> 6] = ss;
  __syncthreads();
  float inv = rsqrtf((parts[0] + parts[1] + parts[2] + parts[3]) * (1.f / 1536.f) + 1e-6f);
  const float4* w4 = (const float4*)w;
  for (int i = threadIdx.x; i < 384; i += 256) {
    float4 v = x4[i];
    float4 ww = w4[i];
    bf16x4v o = {(bf16_t)(v.x * inv * ww.x), (bf16_t)(v.y * inv * ww.y),
                 (bf16_t)(v.z * inv * ww.z), (bf16_t)(v.w * inv * ww.w)};
    *(bf16x4v*)(out + (size_t)row * 1536 + i * 4) = o;
  }
}

// ---------------- kv_all row: RMSNorm(512)->kvn, rope(k_pe 64)->K[*][128..191] ----------------
__global__ __launch_bounds__(256) void k_kv_norm_rope(const float* __restrict__ kvall,
                                                      const float* __restrict__ w,
                                                      const float* __restrict__ freqs,
                                                      bf16_t* __restrict__ kvn,
                                                      bf16_t* __restrict__ Kf) {
  int row = blockIdx.x, tid = threadIdx.x;
  int b = row >> 11, s = row & 2047;
  const float* x = kvall + (size_t)row * 576;
  float ss = 0.f;
  float4 v = {0.f, 0.f, 0.f, 0.f};
  if (tid < 128) {
    v = ((const float4*)x)[tid];
    ss = v.x * v.x + v.y * v.y + v.z * v.z + v.w * v.w;
  }
  for (int m = 32; m; m >>= 1) ss += __shfl_xor(ss, m);
  __shared__ float parts[4];
  if ((tid & 63) == 0) parts[tid >> 6] = ss;
  __syncthreads();
  float inv = rsqrtf((parts[0] + parts[1] + parts[2] + parts[3]) * (1.f / 512.f) + 1e-6f);
  if (tid < 128) {
    float4 ww = ((const float4*)w)[tid];
    bf16x4v o = {(bf16_t)(v.x * inv * ww.x), (bf16_t)(v.y * inv * ww.y),
                 (bf16_t)(v.z * inv * ww.z), (bf16_t)(v.w * inv * ww.w)};
    *(bf16x4v*)(kvn + (size_t)row * 512 + tid * 4) = o;
  }
  if (tid < 32) {
    float xr = x[512 + 2 * tid], xi = x[513 + 2 * tid];
    float c = freqs[s * 64 + 2 * tid], sn = freqs[s * 64 + 2 * tid + 1];
    bf16_t o0 = (bf16_t)(xr * c - xi * sn);
    bf16_t o1 = (bf16_t)(xr * sn + xi * c);
#pragma unroll
    for (int h = 0; h < 16; h++) {
      size_t base = ((size_t)(b * 16 + h) * 2048 + s) * 192 + 128 + 2 * tid;
      Kf[base] = o0;
      Kf[base + 1] = o1;
    }
  }
}

// ---------------- q rope + scale: q fp32 [row][3072] -> Q bf16 [b][h][s][192] ----------------
__global__ __launch_bounds__(256) void k_q_rope(const float* __restrict__ q,
                                                const float* __restrict__ freqs,
                                                bf16_t* __restrict__ Q) {
  int row = blockIdx.x;
  int b = row >> 11, s = row & 2047;
  const float* src = q + (size_t)row * 3072;
  const float* fr = freqs + s * 64;
#pragma unroll
  for (int i = 0; i < 12; i++) {
    int idx = i * 256 + threadIdx.x;
    int h = idx / 192, d = idx - h * 192;
    float val;
    if (d < 128) {
      val = src[h * 192 + d];
    } else {
      int p = (d - 128) >> 1;
      float xr = src[h * 192 + 128 + 2 * p], xi = src[h * 192 + 129 + 2 * p];
      float c = fr[2 * p], sn = fr[2 * p + 1];
      val = ((d & 1) == 0) ? (xr * c - xi * sn) : (xr * sn + xi * c);
    }
    Q[((size_t)(b * 16 + h) * 2048 + s) * 192 + d] = (bf16_t)(val * QSCALE);
  }
}

// ---------------- split kv fp32 [row][4096] -> K nope [b][h][s][0..127], Vt [b][h][d][s] ----------------
__global__ __launch_bounds__(256) void k_split_kv(const float* __restrict__ kvfull,
                                                  bf16_t* __restrict__ Kf,
                                                  bf16_t* __restrict__ Vt) {
  __shared__ bf16_t vt_l[128][66];
  int s0 = blockIdx.x * 64;
  int h = blockIdx.y;
#pragma unroll 4
  for (int i = 0; i < 32; i++) {
    int idx = i * 256 + threadIdx.x;
    int r = idx >> 7, d = idx & 127;
    int row = s0 + r;
    int b = row >> 11, s = row & 2047;
    const float* src = kvfull + (size_t)row * 4096 + h * 256;
    float kn = src[d], vv = src[128 + d];
    Kf[((size_t)(b * 16 + h) * 2048 + s) * 192 + d] = (bf16_t)kn;
    vt_l[d][r] = (bf16_t)vv;
  }
  __syncthreads();
#pragma unroll 4
  for (int i = 0; i < 32; i++) {
    int idx = i * 256 + threadIdx.x;
    int d = idx >> 6, ss = idx & 63;
    int row = s0 + ss;
    int b = row >> 11, s = row & 2047;
    Vt[((size_t)(b * 16 + h) * 128 + d) * 2048 + s] = vt_l[d][ss];
  }
}

// ---------------- flash attention v2: swapped QK^T, lane-local softmax ----------------
// 4 independent waves/block, each wave: 16 q-rows, KBLK=64, causal.
// Q,K: [b*16+h][s][192] bf16 (Q pre-scaled by 192^-.5*log2e); Vt: [b*16+h][d][s];
// O: [b*2048+s][h*128+d].
// Swapped: mfma(K_frag, Q_frag) -> S^T: col(lane&15)=q, row(lk*4+r within 16-grp)=key.
// Softmax per q is 15 in-lane ops + 2 shuffles. P goes through per-wave LDS for the
// PV A-fragment (rows=q, k-major contiguous).
__global__ __launch_bounds__(256) void k_attn(const bf16_t* __restrict__ Q,
                                              const bf16_t* __restrict__ Kf,
                                              const bf16_t* __restrict__ Vt,
                                              bf16_t* __restrict__ O) {
  __shared__ __align__(16) bf16_t P[4][16][72];
  const int tid = threadIdx.x;
  const int lane = tid & 63, wid = tid >> 6;
  const int lr = lane & 15, lk = lane >> 4;
  const int qb = blockIdx.x * 64 + wid * 16;
  const int bh = blockIdx.y;
  const int b = bh >> 4, h = bh & 15;
  const bf16_t* Qb = Q + (size_t)bh * 2048 * 192;
  const bf16_t* Kb = Kf + (size_t)bh * 2048 * 192;
  const bf16_t* Vb = Vt + (size_t)bh * 128 * 2048;
  // Q as B-operand: B[k][col=q]: col=lane&15 -> q, k=(lane>>4)*8+reg
  bf16x8 bq[6];
#pragma unroll
  for (int f = 0; f < 6; f++)
    bq[f] = *(const bf16x8*)(Qb + (size_t)(qb + lr) * 192 + f * 32 + lk * 8);
  f32x4 acc[8] = {};
  float m_s = -1e30f, l_s = 0.f;
  const int q_mine = qb + lr;
  const int nkt = (qb + 15) / 64 + 1;
  for (int kt = 0; kt < nkt; kt++) {
    const int k0 = kt * 64;
    f32x4 sc[4];
#pragma unroll
    for (int hh = 0; hh < 4; hh++) {
      f32x4 a = {};
      const bf16_t* kr = Kb + (size_t)(k0 + hh * 16 + lr) * 192 + lk * 8;
#pragma unroll
      for (int f = 0; f < 6; f++) {
        bf16x8 ak = *(const bf16x8*)(kr + f * 32);
        a = __builtin_amdgcn_mfma_f32_16x16x32_bf16(ak, bq[f], a, 0, 0, 0);
      }
      sc[hh] = a;
    }
    if (k0 + 63 > qb) { // diagonal region: causal mask (key > q)
#pragma unroll
      for (int hh = 0; hh < 4; hh++) {
        int key = k0 + hh * 16 + lk * 4;
#pragma unroll
        for (int r = 0; r < 4; r++)
          if (key + r > q_mine) sc[hh][r] = -1e30f;
      }
    }
    // tile max for my q-column: 15 in-lane + 2 cross-group shuffles
    float t0 = fmaxf(fmaxf(sc[0][0], sc[0][1]), fmaxf(sc[0][2], sc[0][3]));
    float t1 = fmaxf(fmaxf(sc[1][0], sc[1][1]), fmaxf(sc[1][2], sc[1][3]));
    float t2 = fmaxf(fmaxf(sc[2][0], sc[2][1]), fmaxf(sc[2][2], sc[2][3]));
    float t3 = fmaxf(fmaxf(sc[3][0], sc[3][1]), fmaxf(sc[3][2], sc[3][3]));
    float tmax = fmaxf(fmaxf(t0, t1), fmaxf(t2, t3));
    tmax = fmaxf(tmax, __shfl_xor(tmax, 16));
    tmax = fmaxf(tmax, __shfl_xor(tmax, 32));
    float mn = fmaxf(m_s, tmax);
    float alpha = exp2f(m_s - mn);
    m_s = mn;
    float sm = 0.f;
#pragma unroll
    for (int hh = 0; hh < 4; hh++) {
#pragma unroll
      for (int r = 0; r < 4; r++) {
        float p = exp2f(sc[hh][r] - mn);
        sc[hh][r] = p;
        sm += p;
      }
    }
    sm += __shfl_xor(sm, 16);
    sm += __shfl_xor(sm, 32);
    l_s = l_s * alpha + sm;
    // P^T -> LDS: lane has P[q=lr][k0+hh*16+lk*4+r]
#pragma unroll
    for (int hh = 0; hh < 4; hh++) {
      bf16x4v pv = {(bf16_t)sc[hh][0], (bf16_t)sc[hh][1], (bf16_t)sc[hh][2], (bf16_t)sc[hh][3]};
      *(bf16x4v*)(&P[wid][lr][hh * 16 + lk * 4]) = pv;
    }
    // rescale O accumulator: acc rows are q = lk*4+r -> broadcast alpha from lane lk*4+r
    float ab[4];
#pragma unroll
    for (int r = 0; r < 4; r++) ab[r] = __shfl(alpha, lk * 4 + r);
#pragma unroll
    for (int j = 0; j < 8; j++)
#pragma unroll
      for (int r = 0; r < 4; r++) acc[j][r] *= ab[r];
    // PV: A=P (rows=q), B=V (cols=d); two K=32 halves
#pragma unroll
    for (int s2 = 0; s2 < 2; s2++) {
      bf16x8 pa = *(const bf16x8*)(&P[wid][lr][s2 * 32 + lk * 8]);
      const bf16_t* vr = Vb + (size_t)lr * 2048 + k0 + s2 * 32 + lk * 8;
#pragma unroll
      for (int j = 0; j < 8; j++) {
        bf16x8 bv = *(const bf16x8*)(vr + (size_t)j * 16 * 2048);
        acc[j] = __builtin_amdgcn_mfma_f32_16x16x32_bf16(pa, bv, acc[j], 0, 0, 0);
      }
    }
  }
  float linv = 1.f / l_s;
  float lb[4];
#pragma unroll
  for (int r = 0; r < 4; r++) lb[r] = __shfl(linv, lk * 4 + r);
  size_t orow = (size_t)b * 2048 + qb + lk * 4;
#pragma unroll
  for (int j = 0; j < 8; j++)
#pragma unroll
    for (int r = 0; r < 4; r++)
      O[(orow + r) * 2048 + h * 128 + j * 16 + lr] = (bf16_t)(acc[j][r] * lb[r]);
}

extern "C" void kernel_launch(void* const* d_in, const int* in_sizes, int n_in,
                              void* d_out, int out_size, void* d_ws, size_t ws_size,
                              hipStream_t stream) {
  const float* x = (const float*)d_in[0];
  const float* freqs = (const float*)d_in[1];
  const float* wq_a = (const float*)d_in[2];
  const float* q_norm_w = (const float*)d_in[3];
  const float* wq_b = (const float*)d_in[4];
  const float* wkv_a = (const float*)d_in[5];
  const float* kv_norm_w = (const float*)d_in[6];
  const float* wkv_b = (const float*)d_in[7];
  const float* wo = (const float*)d_in[8];
  float* out = (float*)d_out;
  char* ws = (char*)d_ws;

  // fp32 scratch (64MB region) time-shared: kv_all -> kv_full -> q_a -> q
  float* f32scr = (float*)(ws);
  bf16_t* xbf = (bf16_t*)(ws + 67108864);
  bf16_t* wqab = (bf16_t*)(ws + 83886080);
  bf16_t* wqbb = (bf16_t*)(ws + 90177536);
  bf16_t* wkvab = (bf16_t*)(ws + 99614720);
  bf16_t* wkvbb = (bf16_t*)(ws + 101974016);
  bf16_t* wob = (bf16_t*)(ws + 106168320);
  bf16_t* qan = (bf16_t*)(ws + 114556928);
  bf16_t* kvn = (bf16_t*)(ws + 127139840);
  bf16_t* Qb = (bf16_t*)(ws + 131334144);
  bf16_t* Kb = (bf16_t*)(ws + 156499968);
  bf16_t* Vtb = (bf16_t*)(ws + 181665792);
  bf16_t* aob = (bf16_t*)(ws + 198443008);
  (void)in_sizes; (void)n_in; (void)out_size; (void)ws_size;

  auto cast = [&](const float* src, bf16_t* dst, int n) {
    int n8 = n / 8;
    k_cast_bf16<<<(n8 + 255) / 256, 256, 0, stream>>>(src, dst, n8);
  };
  cast(x, xbf, 8388608);
  cast(wq_a, wqab, 3145728);
  cast(wq_b, wqbb, 4718592);
  cast(wkv_a, wkvab, 1179648);
  cast(wkv_b, wkvbb, 2097152);
  cast(wo, wob, 4194304);

  // KV branch
  k_gemm<<<dim3(5, 32), 256, 0, stream>>>(xbf, wkvab, f32scr, 4096, 576, 2048);
  k_kv_norm_rope<<<4096, 256, 0, stream>>>(f32scr, kv_norm_w, freqs, kvn, Kb);
  k_gemm<<<dim3(32, 32), 256, 0, stream>>>(kvn, wkvbb, f32scr, 4096, 4096, 512);
  k_split_kv<<<dim3(64, 16), 256, 0, stream>>>(f32scr, Kb, Vtb);
  // Q branch
  k_gemm<<<dim3(12, 32), 256, 0, stream>>>(xbf, wqab, f32scr, 4096, 1536, 2048);
  k_rms_q<<<4096, 256, 0, stream>>>(f32scr, q_norm_w, qan);
  k_gemm<<<dim3(24, 32), 256, 0, stream>>>(qan, wqbb, f32scr, 4096, 3072, 1536);
  k_q_rope<<<4096, 256, 0, stream>>>(f32scr, freqs, Qb);
  // Attention
  k_attn<<<dim3(32, 32), 256, 0, stream>>>(Qb, Kb, Vtb, aob);
  // Output projection -> d_out (fp32)
  k_gemm<<<dim3(16, 32), 256, 0, stream>>>(aob, wob, out, 4096, 2048, 2048);
}

// Round 4
// 582.759 us; speedup vs baseline: 1.7875x; 1.7875x over previous
//
#include <hip/hip_runtime.h>

typedef __bf16 bf16_t;
typedef bf16_t bf16x8 __attribute__((ext_vector_type(8)));
typedef bf16_t bf16x4v __attribute__((ext_vector_type(4)));
typedef float f32x4 __attribute__((ext_vector_type(4)));

// B=2, S=2048, HID=2048, H=16, Q_LORA=1536, KV_LORA=512, D_NOPE=128, D_ROPE=64, D_V=128, D_QK=192
static constexpr float QSCALE = 0.07216878364870323f * 1.44269504088896341f; // 192^-0.5 * log2(e)

#define AS1 __attribute__((address_space(1)))
#define AS3 __attribute__((address_space(3)))
__device__ __forceinline__ void g2lds16(const void* g, void* l) {
  __builtin_amdgcn_global_load_lds((const AS1 void*)g, (AS3 void*)l, 16, 0, 0);
}

// ---------------- cast fp32 -> bf16 (8 elems/thread) ----------------
__global__ void k_cast_bf16(const float* __restrict__ in, bf16_t* __restrict__ out, int n8) {
  int i = blockIdx.x * 256 + threadIdx.x;
  if (i >= n8) return;
  const float4* p = (const float4*)in + (size_t)i * 2;
  float4 a = p[0], b = p[1];
  bf16x8 o = {(bf16_t)a.x, (bf16_t)a.y, (bf16_t)a.z, (bf16_t)a.w,
              (bf16_t)b.x, (bf16_t)b.y, (bf16_t)b.z, (bf16_t)b.w};
  ((bf16x8*)out)[i] = o;
}

// ---------------- generic bf16 GEMM: C(MxN) = A(MxK) * Bt(NxK)^T ----------------
// 128x128 tile, BK=32, 4 waves. global_load_lds width=16 staging into linear [128][32].
__global__ __launch_bounds__(256) void k_gemm(
    const bf16_t* __restrict__ A, const bf16_t* __restrict__ Bt,
    float* __restrict__ C, int M, int N, int K) {
  __shared__ __align__(16) bf16_t As[128][32];
  __shared__ __align__(16) bf16_t Bs[128][32];
  const int tid = threadIdx.x;
  const int lane = tid & 63, wid = tid >> 6;
  const int wr = wid >> 1, wc = wid & 1;
  const int lr = lane & 15, lk = lane >> 4;
  const int bm = blockIdx.y * 128, bn = blockIdx.x * 128;
  f32x4 acc[4][4] = {};
  const int srow = wid * 16 + (lane >> 2);
  const int scol = (lane & 3) * 8;
  const bf16_t* a0 = A + (size_t)(bm + srow) * K + scol;
  const bf16_t* a1 = A + (size_t)(bm + 64 + srow) * K + scol;
  const bf16_t* b0 = Bt + (size_t)(bn + srow) * K + scol;       // OOB rows (N=576 case) read
  const bf16_t* b1 = Bt + (size_t)(bn + 64 + srow) * K + scol;  // adjacent ws; masked at store
  bf16_t* lA0 = &As[wid * 16][0];
  bf16_t* lA1 = &As[64 + wid * 16][0];
  bf16_t* lB0 = &Bs[wid * 16][0];
  bf16_t* lB1 = &Bs[64 + wid * 16][0];
  for (int kt = 0; kt < K; kt += 32) {
    g2lds16(a0 + kt, lA0);
    g2lds16(a1 + kt, lA1);
    g2lds16(b0 + kt, lB0);
    g2lds16(b1 + kt, lB1);
    __syncthreads();
    bf16x8 af[4], bff[4];
#pragma unroll
    for (int i = 0; i < 4; i++)
      af[i] = *(const bf16x8*)(&As[wr * 64 + i * 16 + lr][lk * 8]);
#pragma unroll
    for (int j = 0; j < 4; j++)
      bff[j] = *(const bf16x8*)(&Bs[wc * 64 + j * 16 + lr][lk * 8]);
#pragma unroll
    for (int i = 0; i < 4; i++)
#pragma unroll
      for (int j = 0; j < 4; j++)
        acc[i][j] = __builtin_amdgcn_mfma_f32_16x16x32_bf16(af[i], bff[j], acc[i][j], 0, 0, 0);
    __syncthreads();
  }
  const int crow = bm + wr * 64 + lk * 4;
  const int ccol = bn + wc * 64 + lr;
#pragma unroll
  for (int i = 0; i < 4; i++)
#pragma unroll
    for (int j = 0; j < 4; j++) {
      int col = ccol + j * 16;
      if (col < N) {
#pragma unroll
        for (int r = 0; r < 4; r++)
          C[(size_t)(crow + i * 16 + r) * N + col] = acc[i][j][r];
      }
    }
}

// ---------------- RMSNorm over 1536 (q_a) -> bf16 ----------------
__global__ __launch_bounds__(256) void k_rms_q(const float* __restrict__ in,
                                               const float* __restrict__ w,
                                               bf16_t* __restrict__ out) {
  int row = blockIdx.x;
  const float4* x4 = (const float4*)(in + (size_t)row * 1536);
  float ss = 0.f;
  for (int i = threadIdx.x; i < 384; i += 256) {
    float4 v = x4[i];
    ss += v.x * v.x + v.y * v.y + v.z * v.z + v.w * v.w;
  }
  for (int m = 32; m; m >>= 1) ss += __shfl_xor(ss, m);
  __shared__ float parts[4];
  if ((threadIdx.x & 63) == 0) parts[threadIdx.x >> 6] = ss;
  __syncthreads();
  float inv = rsqrtf((parts[0] + parts[1] + parts[2] + parts[3]) * (1.f / 1536.f) + 1e-6f);
  const float4* w4 = (const float4*)w;
  for (int i = threadIdx.x; i < 384; i += 256) {
    float4 v = x4[i];
    float4 ww = w4[i];
    bf16x4v o = {(bf16_t)(v.x * inv * ww.x), (bf16_t)(v.y * inv * ww.y),
                 (bf16_t)(v.z * inv * ww.z), (bf16_t)(v.w * inv * ww.w)};
    *(bf16x4v*)(out + (size_t)row * 1536 + i * 4) = o;
  }
}

// ---------------- kv_all row: RMSNorm(512)->kvn, rope(k_pe 64)->K[*][128..191] ----------------
__global__ __launch_bounds__(256) void k_kv_norm_rope(const float* __restrict__ kvall,
                                                      const float* __restrict__ w,
                                                      const float* __restrict__ freqs,
                                                      bf16_t* __restrict__ kvn,
                                                      bf16_t* __restrict__ Kf) {
  int row = blockIdx.x, tid = threadIdx.x;
  int b = row >> 11, s = row & 2047;
  const float* x = kvall + (size_t)row * 576;
  float ss = 0.f;
  float4 v = {0.f, 0.f, 0.f, 0.f};
  if (tid < 128) {
    v = ((const float4*)x)[tid];
    ss = v.x * v.x + v.y * v.y + v.z * v.z + v.w * v.w;
  }
  for (int m = 32; m; m >>= 1) ss += __shfl_xor(ss, m);
  __shared__ float parts[4];
  if ((tid & 63) == 0) parts[tid >> 6] = ss;
  __syncthreads();
  float inv = rsqrtf((parts[0] + parts[1] + parts[2] + parts[3]) * (1.f / 512.f) + 1e-6f);
  if (tid < 128) {
    float4 ww = ((const float4*)w)[tid];
    bf16x4v o = {(bf16_t)(v.x * inv * ww.x), (bf16_t)(v.y * inv * ww.y),
                 (bf16_t)(v.z * inv * ww.z), (bf16_t)(v.w * inv * ww.w)};
    *(bf16x4v*)(kvn + (size_t)row * 512 + tid * 4) = o;
  }
  if (tid < 32) {
    float xr = x[512 + 2 * tid], xi = x[513 + 2 * tid];
    float c = freqs[s * 64 + 2 * tid], sn = freqs[s * 64 + 2 * tid + 1];
    bf16_t o0 = (bf16_t)(xr * c - xi * sn);
    bf16_t o1 = (bf16_t)(xr * sn + xi * c);
#pragma unroll
    for (int h = 0; h < 16; h++) {
      size_t base = ((size_t)(b * 16 + h) * 2048 + s) * 192 + 128 + 2 * tid;
      Kf[base] = o0;
      Kf[base + 1] = o1;
    }
  }
}

// ---------------- q rope + scale: q fp32 [row][3072] -> Q bf16 [b][h][s][192] ----------------
__global__ __launch_bounds__(256) void k_q_rope(const float* __restrict__ q,
                                                const float* __restrict__ freqs,
                                                bf16_t* __restrict__ Q) {
  int row = blockIdx.x;
  int b = row >> 11, s = row & 2047;
  const float* src = q + (size_t)row * 3072;
  const float* fr = freqs + s * 64;
#pragma unroll
  for (int i = 0; i < 12; i++) {
    int idx = i * 256 + threadIdx.x;
    int h = idx / 192, d = idx - h * 192;
    float val;
    if (d < 128) {
      val = src[h * 192 + d];
    } else {
      int p = (d - 128) >> 1;
      float xr = src[h * 192 + 128 + 2 * p], xi = src[h * 192 + 129 + 2 * p];
      float c = fr[2 * p], sn = fr[2 * p + 1];
      val = ((d & 1) == 0) ? (xr * c - xi * sn) : (xr * sn + xi * c);
    }
    Q[((size_t)(b * 16 + h) * 2048 + s) * 192 + d] = (bf16_t)(val * QSCALE);
  }
}

// ---------------- split kv fp32 [row][4096] -> K nope [b][h][s][0..127], Vt [b][h][d][s] ----------------
__global__ __launch_bounds__(256) void k_split_kv(const float* __restrict__ kvfull,
                                                  bf16_t* __restrict__ Kf,
                                                  bf16_t* __restrict__ Vt) {
  __shared__ bf16_t vt_l[128][66];
  int s0 = blockIdx.x * 64;
  int h = blockIdx.y;
#pragma unroll 4
  for (int i = 0; i < 32; i++) {
    int idx = i * 256 + threadIdx.x;
    int r = idx >> 7, d = idx & 127;
    int row = s0 + r;
    int b = row >> 11, s = row & 2047;
    const float* src = kvfull + (size_t)row * 4096 + h * 256;
    float kn = src[d], vv = src[128 + d];
    Kf[((size_t)(b * 16 + h) * 2048 + s) * 192 + d] = (bf16_t)kn;
    vt_l[d][r] = (bf16_t)vv;
  }
  __syncthreads();
#pragma unroll 4
  for (int i = 0; i < 32; i++) {
    int idx = i * 256 + threadIdx.x;
    int d = idx >> 6, ss = idx & 63;
    int row = s0 + ss;
    int b = row >> 11, s = row & 2047;
    Vt[((size_t)(b * 16 + h) * 128 + d) * 2048 + s] = vt_l[d][ss];
  }
}

// ---------------- flash attention v3: LDS-staged K/V shared by 4 waves ----------------
// Block: 256 thr = 4 waves, QBLK=64 (16 q-rows/wave), KBLK=64, causal, heavy tiles first.
// K staged as 3 panels [64][64] bf16, V as [128][64]; both XOR-swizzled (chunk ^= row&7)
// via pre-swizzled GLOBAL source (linear LDS dest, rule: both-sides-or-neither).
// Swapped QK^T (mfma(K,Q)) -> lane-local softmax; P via per-wave LDS; PV from staged V.
__global__ __launch_bounds__(256) void k_attn(const bf16_t* __restrict__ Q,
                                              const bf16_t* __restrict__ Kf,
                                              const bf16_t* __restrict__ Vt,
                                              bf16_t* __restrict__ O) {
  __shared__ __align__(16) bf16_t Ks[3][64][64];
  __shared__ __align__(16) bf16_t Vs[128][64];
  __shared__ __align__(16) bf16_t P[4][16][72];
  const int tid = threadIdx.x;
  const int lane = tid & 63, wid = tid >> 6;
  const int lr = lane & 15, lk = lane >> 4;
  const int qt = (int)gridDim.x - 1 - (int)blockIdx.x; // heavy blocks dispatch first
  const int qb = qt * 64;
  const int qbw = qb + wid * 16;
  const int bh = blockIdx.y;
  const int b = bh >> 4, h = bh & 15;
  const bf16_t* Qb = Q + (size_t)bh * 2048 * 192;
  const bf16_t* Kb = Kf + (size_t)bh * 2048 * 192;
  const bf16_t* Vb = Vt + (size_t)bh * 128 * 2048;
  // Q as B-operand (col=q=lr, k=lk*8+reg)
  bf16x8 bq[6];
#pragma unroll
  for (int f = 0; f < 6; f++)
    bq[f] = *(const bf16x8*)(Qb + (size_t)(qbw + lr) * 192 + f * 32 + lk * 8);
  f32x4 acc[8] = {};
  float m_s = -1e30f, l_s = 0.f;
  const int q_mine = qbw + lr;
  const int srowb = tid >> 3; // 0..31
  const int sc8 = tid & 7;    // chunk 0..7
  auto stage = [&](int k0) {
#pragma unroll
    for (int p = 0; p < 3; p++)
#pragma unroll
      for (int hh2 = 0; hh2 < 2; hh2++) {
        int row = hh2 * 32 + srowb;
        g2lds16(Kb + (size_t)(k0 + row) * 192 + p * 64 + ((sc8 ^ (row & 7)) * 8),
                &Ks[p][row][sc8 * 8]);
      }
#pragma unroll
    for (int j = 0; j < 4; j++) {
      int d = j * 32 + srowb;
      g2lds16(Vb + (size_t)d * 2048 + k0 + ((sc8 ^ (d & 7)) * 8), &Vs[d][sc8 * 8]);
    }
  };
  const int nkt = qt + 1;
  stage(0);
  for (int kt = 0; kt < nkt; kt++) {
    const int k0 = kt * 64;
    __syncthreads(); // staged tile visible (syncthreads drains vmcnt)
    f32x4 sc[4];
#pragma unroll
    for (int hh = 0; hh < 4; hh++) {
      f32x4 a = {};
      const int row = hh * 16 + lr;
      const int sw = (row & 7);
#pragma unroll
      for (int f = 0; f < 6; f++) {
        const int cc = (f & 1) * 4 + lk;
        bf16x8 ak = *(const bf16x8*)(&Ks[f >> 1][row][(cc ^ sw) * 8]);
        a = __builtin_amdgcn_mfma_f32_16x16x32_bf16(ak, bq[f], a, 0, 0, 0);
      }
      sc[hh] = a;
    }
    if (k0 + 63 > qbw) { // diagonal region for this wave: mask key > q
#pragma unroll
      for (int hh = 0; hh < 4; hh++) {
        int key = k0 + hh * 16 + lk * 4;
#pragma unroll
        for (int r = 0; r < 4; r++)
          if (key + r > q_mine) sc[hh][r] = -1e30f;
      }
    }
    // softmax for my q-column: 15 in-lane max + 2 shuffles
    float t0 = fmaxf(fmaxf(sc[0][0], sc[0][1]), fmaxf(sc[0][2], sc[0][3]));
    float t1 = fmaxf(fmaxf(sc[1][0], sc[1][1]), fmaxf(sc[1][2], sc[1][3]));
    float t2 = fmaxf(fmaxf(sc[2][0], sc[2][1]), fmaxf(sc[2][2], sc[2][3]));
    float t3 = fmaxf(fmaxf(sc[3][0], sc[3][1]), fmaxf(sc[3][2], sc[3][3]));
    float tmax = fmaxf(fmaxf(t0, t1), fmaxf(t2, t3));
    tmax = fmaxf(tmax, __shfl_xor(tmax, 16));
    tmax = fmaxf(tmax, __shfl_xor(tmax, 32));
    float mn = fmaxf(m_s, tmax);
    float alpha = exp2f(m_s - mn);
    m_s = mn;
    float sm = 0.f;
#pragma unroll
    for (int hh = 0; hh < 4; hh++) {
#pragma unroll
      for (int r = 0; r < 4; r++) {
        float p = exp2f(sc[hh][r] - mn);
        sc[hh][r] = p;
        sm += p;
      }
    }
    sm += __shfl_xor(sm, 16);
    sm += __shfl_xor(sm, 32);
    l_s = l_s * alpha + sm;
    // P^T -> per-wave LDS: lane holds P[q=lr][k=hh*16+lk*4+r]
#pragma unroll
    for (int hh = 0; hh < 4; hh++) {
      bf16x4v pv = {(bf16_t)sc[hh][0], (bf16_t)sc[hh][1], (bf16_t)sc[hh][2], (bf16_t)sc[hh][3]};
      *(bf16x4v*)(&P[wid][lr][hh * 16 + lk * 4]) = pv;
    }
    float ab[4];
#pragma unroll
    for (int r = 0; r < 4; r++) ab[r] = __shfl(alpha, lk * 4 + r);
#pragma unroll
    for (int j = 0; j < 8; j++)
#pragma unroll
      for (int r = 0; r < 4; r++) acc[j][r] *= ab[r];
    // PV: A=P (row=q), B=V^T from staged Vs (row=d, swizzled)
#pragma unroll
    for (int s2 = 0; s2 < 2; s2++) {
      bf16x8 pa = *(const bf16x8*)(&P[wid][lr][s2 * 32 + lk * 8]);
#pragma unroll
      for (int j = 0; j < 8; j++) {
        const int d = j * 16 + lr;
        const int cc = s2 * 4 + lk;
        bf16x8 bv = *(const bf16x8*)(&Vs[d][(cc ^ (d & 7)) * 8]);
        acc[j] = __builtin_amdgcn_mfma_f32_16x16x32_bf16(pa, bv, acc[j], 0, 0, 0);
      }
    }
    __syncthreads(); // all waves done reading staged tile
    if (kt + 1 < nkt) stage(k0 + 64);
  }
  float linv = 1.f / l_s;
  float lb[4];
#pragma unroll
  for (int r = 0; r < 4; r++) lb[r] = __shfl(linv, lk * 4 + r);
  size_t orow = (size_t)b * 2048 + qbw + lk * 4;
#pragma unroll
  for (int j = 0; j < 8; j++)
#pragma unroll
    for (int r = 0; r < 4; r++)
      O[(orow + r) * 2048 + h * 128 + j * 16 + lr] = (bf16_t)(acc[j][r] * lb[r]);
}

extern "C" void kernel_launch(void* const* d_in, const int* in_sizes, int n_in,
                              void* d_out, int out_size, void* d_ws, size_t ws_size,
                              hipStream_t stream) {
  const float* x = (const float*)d_in[0];
  const float* freqs = (const float*)d_in[1];
  const float* wq_a = (const float*)d_in[2];
  const float* q_norm_w = (const float*)d_in[3];
  const float* wq_b = (const float*)d_in[4];
  const float* wkv_a = (const float*)d_in[5];
  const float* kv_norm_w = (const float*)d_in[6];
  const float* wkv_b = (const float*)d_in[7];
  const float* wo = (const float*)d_in[8];
  float* out = (float*)d_out;
  char* ws = (char*)d_ws;

  // fp32 scratch (64MB region) time-shared: kv_all -> kv_full -> q_a -> q
  float* f32scr = (float*)(ws);
  bf16_t* xbf = (bf16_t*)(ws + 67108864);
  bf16_t* wqab = (bf16_t*)(ws + 83886080);
  bf16_t* wqbb = (bf16_t*)(ws + 90177536);
  bf16_t* wkvab = (bf16_t*)(ws + 99614720);
  bf16_t* wkvbb = (bf16_t*)(ws + 101974016);
  bf16_t* wob = (bf16_t*)(ws + 106168320);
  bf16_t* qan = (bf16_t*)(ws + 114556928);
  bf16_t* kvn = (bf16_t*)(ws + 127139840);
  bf16_t* Qb = (bf16_t*)(ws + 131334144);
  bf16_t* Kb = (bf16_t*)(ws + 156499968);
  bf16_t* Vtb = (bf16_t*)(ws + 181665792);
  bf16_t* aob = (bf16_t*)(ws + 198443008);
  (void)in_sizes; (void)n_in; (void)out_size; (void)ws_size;

  auto cast = [&](const float* src, bf16_t* dst, int n) {
    int n8 = n / 8;
    k_cast_bf16<<<(n8 + 255) / 256, 256, 0, stream>>>(src, dst, n8);
  };
  cast(x, xbf, 8388608);
  cast(wq_a, wqab, 3145728);
  cast(wq_b, wqbb, 4718592);
  cast(wkv_a, wkvab, 1179648);
  cast(wkv_b, wkvbb, 2097152);
  cast(wo, wob, 4194304);

  // KV branch
  k_gemm<<<dim3(5, 32), 256, 0, stream>>>(xbf, wkvab, f32scr, 4096, 576, 2048);
  k_kv_norm_rope<<<4096, 256, 0, stream>>>(f32scr, kv_norm_w, freqs, kvn, Kb);
  k_gemm<<<dim3(32, 32), 256, 0, stream>>>(kvn, wkvbb, f32scr, 4096, 4096, 512);
  k_split_kv<<<dim3(64, 16), 256, 0, stream>>>(f32scr, Kb, Vtb);
  // Q branch
  k_gemm<<<dim3(12, 32), 256, 0, stream>>>(xbf, wqab, f32scr, 4096, 1536, 2048);
  k_rms_q<<<4096, 256, 0, stream>>>(f32scr, q_norm_w, qan);
  k_gemm<<<dim3(24, 32), 256, 0, stream>>>(qan, wqbb, f32scr, 4096, 3072, 1536);
  k_q_rope<<<4096, 256, 0, stream>>>(f32scr, freqs, Qb);
  // Attention
  k_attn<<<dim3(32, 32), 256, 0, stream>>>(Qb, Kb, Vtb, aob);
  // Output projection -> d_out (fp32)
  k_gemm<<<dim3(16, 32), 256, 0, stream>>>(aob, wob, out, 4096, 2048, 2048);
}

// Round 5
// 579.784 us; speedup vs baseline: 1.7967x; 1.0051x over previous
//
#include <hip/hip_runtime.h>

typedef __bf16 bf16_t;
typedef bf16_t bf16x8 __attribute__((ext_vector_type(8)));
typedef bf16_t bf16x4v __attribute__((ext_vector_type(4)));
typedef float f32x4 __attribute__((ext_vector_type(4)));

// B=2, S=2048, HID=2048, H=16, Q_LORA=1536, KV_LORA=512, D_NOPE=128, D_ROPE=64, D_V=128, D_QK=192
static constexpr float QSCALE = 0.07216878364870323f * 1.44269504088896341f; // 192^-0.5 * log2(e)

#define AS1 __attribute__((address_space(1)))
#define AS3 __attribute__((address_space(3)))
__device__ __forceinline__ void g2lds16(const void* g, void* l) {
  __builtin_amdgcn_global_load_lds((const AS1 void*)g, (AS3 void*)l, 16, 0, 0);
}

// ---------------- cast fp32 -> bf16 (8 elems/thread) ----------------
__global__ void k_cast_bf16(const float* __restrict__ in, bf16_t* __restrict__ out, int n8) {
  int i = blockIdx.x * 256 + threadIdx.x;
  if (i >= n8) return;
  const float4* p = (const float4*)in + (size_t)i * 2;
  float4 a = p[0], b = p[1];
  bf16x8 o = {(bf16_t)a.x, (bf16_t)a.y, (bf16_t)a.z, (bf16_t)a.w,
              (bf16_t)b.x, (bf16_t)b.y, (bf16_t)b.z, (bf16_t)b.w};
  ((bf16x8*)out)[i] = o;
}

// ---------------- generic bf16 GEMM: C(MxN) = A(MxK) * Bt(NxK)^T ----------------
// 128x128 tile, BK=32, 4 waves. global_load_lds width=16 staging into linear [128][32].
// MODE 0: C fp32.  MODE 1: C bf16.  MODE 2: fused q rope+scale -> Qb bf16 [b*16+h][s][192].
template <int MODE>
__global__ __launch_bounds__(256) void k_gemm_t(
    const bf16_t* __restrict__ A, const bf16_t* __restrict__ Bt,
    void* __restrict__ Cout, int M, int N, int K, const float* __restrict__ freqs) {
  __shared__ __align__(16) bf16_t As[128][32];
  __shared__ __align__(16) bf16_t Bs[128][32];
  const int tid = threadIdx.x;
  const int lane = tid & 63, wid = tid >> 6;
  const int wr = wid >> 1, wc = wid & 1;
  const int lr = lane & 15, lk = lane >> 4;
  const int bm = blockIdx.y * 128, bn = blockIdx.x * 128;
  f32x4 acc[4][4] = {};
  const int srow = wid * 16 + (lane >> 2);
  const int scol = (lane & 3) * 8;
  const bf16_t* a0 = A + (size_t)(bm + srow) * K + scol;
  const bf16_t* a1 = A + (size_t)(bm + 64 + srow) * K + scol;
  const bf16_t* b0 = Bt + (size_t)(bn + srow) * K + scol;       // OOB rows (N=576 case) read
  const bf16_t* b1 = Bt + (size_t)(bn + 64 + srow) * K + scol;  // adjacent ws; masked at store
  bf16_t* lA0 = &As[wid * 16][0];
  bf16_t* lA1 = &As[64 + wid * 16][0];
  bf16_t* lB0 = &Bs[wid * 16][0];
  bf16_t* lB1 = &Bs[64 + wid * 16][0];
  for (int kt = 0; kt < K; kt += 32) {
    g2lds16(a0 + kt, lA0);
    g2lds16(a1 + kt, lA1);
    g2lds16(b0 + kt, lB0);
    g2lds16(b1 + kt, lB1);
    __syncthreads();
    bf16x8 af[4], bff[4];
#pragma unroll
    for (int i = 0; i < 4; i++)
      af[i] = *(const bf16x8*)(&As[wr * 64 + i * 16 + lr][lk * 8]);
#pragma unroll
    for (int j = 0; j < 4; j++)
      bff[j] = *(const bf16x8*)(&Bs[wc * 64 + j * 16 + lr][lk * 8]);
#pragma unroll
    for (int i = 0; i < 4; i++)
#pragma unroll
      for (int j = 0; j < 4; j++)
        acc[i][j] = __builtin_amdgcn_mfma_f32_16x16x32_bf16(af[i], bff[j], acc[i][j], 0, 0, 0);
    __syncthreads();
  }
  const int crow = bm + wr * 64 + lk * 4;
  const int ccol = bn + wc * 64 + lr;
#pragma unroll
  for (int i = 0; i < 4; i++)
#pragma unroll
    for (int j = 0; j < 4; j++) {
      int col = ccol + j * 16;
      if (col < N) {
        if constexpr (MODE == 0) {
          float* C = (float*)Cout;
#pragma unroll
          for (int r = 0; r < 4; r++)
            C[(size_t)(crow + i * 16 + r) * N + col] = acc[i][j][r];
        } else if constexpr (MODE == 1) {
          bf16_t* C = (bf16_t*)Cout;
#pragma unroll
          for (int r = 0; r < 4; r++)
            C[(size_t)(crow + i * 16 + r) * N + col] = (bf16_t)acc[i][j][r];
        } else {
          // fused rope+scale epilogue -> Qb [b*16+h][s][192]
          bf16_t* Qd = (bf16_t*)Cout;
          int hcol = col / 192;
          int dmod = col - hcol * 192;  // uniform >=128 test per fragment (16 | 192)
#pragma unroll
          for (int r = 0; r < 4; r++) {
            int row = crow + i * 16 + r;
            int bb = row >> 11, s = row & 2047;
            float v = acc[i][j][r];
            float partner = __shfl_xor(v, 1);
            if (dmod >= 128) {
              int p = (dmod - 128) >> 1;
              int pbase = ((lr & 1) == 0) ? (dmod - 128) : (dmod - 129);
              p = pbase >> 1;
              float c = freqs[s * 64 + 2 * p];
              float sn = freqs[s * 64 + 2 * p + 1];
              v = ((lr & 1) == 0) ? (v * c - partner * sn) : (partner * sn + v * c);
            }
            Qd[((size_t)(bb * 16 + hcol) * 2048 + s) * 192 + dmod] = (bf16_t)(v * QSCALE);
          }
        }
      }
    }
}

// ---------------- RMSNorm over 1536 (q_a, bf16 in) -> bf16 ----------------
__global__ __launch_bounds__(256) void k_rms_q(const bf16_t* __restrict__ in,
                                               const float* __restrict__ w,
                                               bf16_t* __restrict__ out) {
  int row = blockIdx.x, tid = threadIdx.x;
  const bf16x8* x8 = (const bf16x8*)(in + (size_t)row * 1536);
  float ss = 0.f;
  bf16x8 v = {};
  if (tid < 192) {
    v = x8[tid];
#pragma unroll
    for (int j = 0; j < 8; j++) { float f = (float)v[j]; ss += f * f; }
  }
  for (int m = 32; m; m >>= 1) ss += __shfl_xor(ss, m);
  __shared__ float parts[4];
  if ((tid & 63) == 0) parts[tid >> 6] = ss;
  __syncthreads();
  float inv = rsqrtf((parts[0] + parts[1] + parts[2] + parts[3]) * (1.f / 1536.f) + 1e-6f);
  if (tid < 192) {
    const float4* w4 = (const float4*)(w + tid * 8);
    float4 w0 = w4[0], w1 = w4[1];
    bf16x8 o = {(bf16_t)((float)v[0] * inv * w0.x), (bf16_t)((float)v[1] * inv * w0.y),
                (bf16_t)((float)v[2] * inv * w0.z), (bf16_t)((float)v[3] * inv * w0.w),
                (bf16_t)((float)v[4] * inv * w1.x), (bf16_t)((float)v[5] * inv * w1.y),
                (bf16_t)((float)v[6] * inv * w1.z), (bf16_t)((float)v[7] * inv * w1.w)};
    *(bf16x8*)(out + (size_t)row * 1536 + tid * 8) = o;
  }
}

// ---------------- kv_all (bf16) row: RMSNorm(512)->kvn, rope(k_pe 64)->K[*][128..191] ----------------
__global__ __launch_bounds__(256) void k_kv_norm_rope(const bf16_t* __restrict__ kvall,
                                                      const float* __restrict__ w,
                                                      const float* __restrict__ freqs,
                                                      bf16_t* __restrict__ kvn,
                                                      bf16_t* __restrict__ Kf) {
  int row = blockIdx.x, tid = threadIdx.x;
  int b = row >> 11, s = row & 2047;
  const bf16_t* x = kvall + (size_t)row * 576;
  float ss = 0.f;
  float vf[4] = {0.f, 0.f, 0.f, 0.f};
  if (tid < 128) {
    bf16x4v v4 = *(const bf16x4v*)(x + tid * 4);
#pragma unroll
    for (int j = 0; j < 4; j++) { vf[j] = (float)v4[j]; ss += vf[j] * vf[j]; }
  }
  for (int m = 32; m; m >>= 1) ss += __shfl_xor(ss, m);
  __shared__ float parts[4];
  if ((tid & 63) == 0) parts[tid >> 6] = ss;
  __syncthreads();
  float inv = rsqrtf((parts[0] + parts[1] + parts[2] + parts[3]) * (1.f / 512.f) + 1e-6f);
  if (tid < 128) {
    float4 ww = ((const float4*)w)[tid];
    bf16x4v o = {(bf16_t)(vf[0] * inv * ww.x), (bf16_t)(vf[1] * inv * ww.y),
                 (bf16_t)(vf[2] * inv * ww.z), (bf16_t)(vf[3] * inv * ww.w)};
    *(bf16x4v*)(kvn + (size_t)row * 512 + tid * 4) = o;
  }
  if (tid < 32) {
    float xr = (float)x[512 + 2 * tid], xi = (float)x[513 + 2 * tid];
    float c = freqs[s * 64 + 2 * tid], sn = freqs[s * 64 + 2 * tid + 1];
    bf16_t o0 = (bf16_t)(xr * c - xi * sn);
    bf16_t o1 = (bf16_t)(xr * sn + xi * c);
#pragma unroll
    for (int h = 0; h < 16; h++) {
      size_t base = ((size_t)(b * 16 + h) * 2048 + s) * 192 + 128 + 2 * tid;
      Kf[base] = o0;
      Kf[base + 1] = o1;
    }
  }
}

// ---------------- split kv bf16 [row][4096] -> K nope [b][h][s][0..127], Vt [b][h][d][s] ----------------
__global__ __launch_bounds__(256) void k_split_kv(const bf16_t* __restrict__ kvfull,
                                                  bf16_t* __restrict__ Kf,
                                                  bf16_t* __restrict__ Vt) {
  __shared__ bf16_t vt_l[128][66];
  int s0 = blockIdx.x * 64;
  int h = blockIdx.y;
#pragma unroll 4
  for (int i = 0; i < 32; i++) {
    int idx = i * 256 + threadIdx.x;
    int r = idx >> 7, d = idx & 127;
    int row = s0 + r;
    int b = row >> 11, s = row & 2047;
    const bf16_t* src = kvfull + (size_t)row * 4096 + h * 256;
    Kf[((size_t)(b * 16 + h) * 2048 + s) * 192 + d] = src[d];
    vt_l[d][r] = src[128 + d];
  }
  __syncthreads();
#pragma unroll 4
  for (int i = 0; i < 32; i++) {
    int idx = i * 256 + threadIdx.x;
    int d = idx >> 6, ss = idx & 63;
    int row = s0 + ss;
    int b = row >> 11, s = row & 2047;
    Vt[((size_t)(b * 16 + h) * 128 + d) * 2048 + s] = vt_l[d][ss];
  }
}

// ---------------- flash attention v4: QBLK=128, 8 waves, T14 reg-staged K/V ----------------
// Block: 512 thr = 8 waves x 16 q-rows, KBLK=64, causal, heavy tiles first.
// K/V loaded to REGS at loop top (latency hides under compute), ds_write'd after the
// read-barrier (swizzled per-lane addresses; ADD-swizzle chunk' = (chunk+row)&7).
// Swapped QK^T (mfma(K,Q)) -> lane-local softmax; P via per-wave LDS; PV from staged V.
__global__ __launch_bounds__(512) void k_attn(const bf16_t* __restrict__ Q,
                                              const bf16_t* __restrict__ Kf,
                                              const bf16_t* __restrict__ Vt,
                                              bf16_t* __restrict__ O) {
  __shared__ __align__(16) bf16_t Ks[3][64][64];
  __shared__ __align__(16) bf16_t Vs[128][64];
  __shared__ __align__(16) bf16_t P[8][16][72];
  const int tid = threadIdx.x;
  const int lane = tid & 63, wid = tid >> 6;
  const int lr = lane & 15, lk = lane >> 4;
  const int qt = (int)gridDim.x - 1 - (int)blockIdx.x; // heavy blocks dispatch first
  const int qb = qt * 128;
  const int qbw = qb + wid * 16;
  const int bh = blockIdx.y;
  const int b = bh >> 4, h = bh & 15;
  const bf16_t* Qp = Q + (size_t)bh * 2048 * 192;
  const bf16_t* Kb = Kf + (size_t)bh * 2048 * 192;
  const bf16_t* Vb = Vt + (size_t)bh * 128 * 2048;
  bf16x8 bq[6];
#pragma unroll
  for (int f = 0; f < 6; f++)
    bq[f] = *(const bf16x8*)(Qp + (size_t)(qbw + lr) * 192 + f * 32 + lk * 8);
  f32x4 acc[8] = {};
  float m_s = -1e30f, l_s = 0.f;
  const int q_mine = qbw + lr;
  // staging: 512 threads, 5 x 16B each (Ks 3 panels [64][64] + Vs [128][64])
  const int krow = tid >> 3;       // 0..63
  const int kc8 = tid & 7;         // chunk
  const int vd1 = 64 + krow;
  bf16x8 kr0, kr1, kr2, vr0, vr1;
  auto issue = [&](int k0) {
    const bf16_t* kp = Kb + (size_t)(k0 + krow) * 192 + kc8 * 8;
    kr0 = *(const bf16x8*)(kp);
    kr1 = *(const bf16x8*)(kp + 64);
    kr2 = *(const bf16x8*)(kp + 128);
    vr0 = *(const bf16x8*)(Vb + (size_t)krow * 2048 + k0 + kc8 * 8);
    vr1 = *(const bf16x8*)(Vb + (size_t)vd1 * 2048 + k0 + kc8 * 8);
  };
  auto commit = [&]() {
    *(bf16x8*)(&Ks[0][krow][((kc8 + krow) & 7) * 8]) = kr0;
    *(bf16x8*)(&Ks[1][krow][((kc8 + krow) & 7) * 8]) = kr1;
    *(bf16x8*)(&Ks[2][krow][((kc8 + krow) & 7) * 8]) = kr2;
    *(bf16x8*)(&Vs[krow][((kc8 + krow) & 7) * 8]) = vr0;
    *(bf16x8*)(&Vs[vd1][((kc8 + vd1) & 7) * 8]) = vr1;
  };
  const int nkt = qt * 2 + 2;
  issue(0);
  commit();
  __syncthreads();
  for (int kt = 0; kt < nkt; kt++) {
    const int k0 = kt * 64;
    if (kt + 1 < nkt) issue(k0 + 64); // overlap next-tile HBM latency with compute
    if (k0 <= qbw + 15) {             // skip fully-masked tiles for this wave
      f32x4 sc[4];
#pragma unroll
      for (int hh = 0; hh < 4; hh++) {
        f32x4 a = {};
        const int row = hh * 16 + lr;
#pragma unroll
        for (int f = 0; f < 6; f++) {
          const int cc = (f & 1) * 4 + lk;
          bf16x8 ak = *(const bf16x8*)(&Ks[f >> 1][row][((cc + row) & 7) * 8]);
          a = __builtin_amdgcn_mfma_f32_16x16x32_bf16(ak, bq[f], a, 0, 0, 0);
        }
        sc[hh] = a;
      }
      if (k0 + 63 > qbw) {
#pragma unroll
        for (int hh = 0; hh < 4; hh++) {
          int key = k0 + hh * 16 + lk * 4;
#pragma unroll
          for (int r = 0; r < 4; r++)
            if (key + r > q_mine) sc[hh][r] = -1e30f;
        }
      }
      float t0 = fmaxf(fmaxf(sc[0][0], sc[0][1]), fmaxf(sc[0][2], sc[0][3]));
      float t1 = fmaxf(fmaxf(sc[1][0], sc[1][1]), fmaxf(sc[1][2], sc[1][3]));
      float t2 = fmaxf(fmaxf(sc[2][0], sc[2][1]), fmaxf(sc[2][2], sc[2][3]));
      float t3 = fmaxf(fmaxf(sc[3][0], sc[3][1]), fmaxf(sc[3][2], sc[3][3]));
      float tmax = fmaxf(fmaxf(t0, t1), fmaxf(t2, t3));
      tmax = fmaxf(tmax, __shfl_xor(tmax, 16));
      tmax = fmaxf(tmax, __shfl_xor(tmax, 32));
      float mn = fmaxf(m_s, tmax);
      float alpha = exp2f(m_s - mn);
      m_s = mn;
      float sm = 0.f;
#pragma unroll
      for (int hh = 0; hh < 4; hh++) {
#pragma unroll
        for (int r = 0; r < 4; r++) {
          float p = exp2f(sc[hh][r] - mn);
          sc[hh][r] = p;
          sm += p;
        }
      }
      sm += __shfl_xor(sm, 16);
      sm += __shfl_xor(sm, 32);
      l_s = l_s * alpha + sm;
      // P -> per-wave LDS (ADD-swizzled 8-chunks)
#pragma unroll
      for (int hh = 0; hh < 4; hh++) {
        int c8 = hh * 2 + (lk >> 1);
        int coff = ((c8 + lr) & 7) * 8 + (lk & 1) * 4;
        bf16x4v pv = {(bf16_t)sc[hh][0], (bf16_t)sc[hh][1], (bf16_t)sc[hh][2], (bf16_t)sc[hh][3]};
        *(bf16x4v*)(&P[wid][lr][coff]) = pv;
      }
      float ab[4];
#pragma unroll
      for (int r = 0; r < 4; r++) ab[r] = __shfl(alpha, lk * 4 + r);
#pragma unroll
      for (int j = 0; j < 8; j++)
#pragma unroll
        for (int r = 0; r < 4; r++) acc[j][r] *= ab[r];
#pragma unroll
      for (int s2 = 0; s2 < 2; s2++) {
        bf16x8 pa = *(const bf16x8*)(&P[wid][lr][((s2 * 4 + lk + lr) & 7) * 8]);
#pragma unroll
        for (int j = 0; j < 8; j++) {
          const int d = j * 16 + lr;
          bf16x8 bv = *(const bf16x8*)(&Vs[d][((s2 * 4 + lk + d) & 7) * 8]);
          acc[j] = __builtin_amdgcn_mfma_f32_16x16x32_bf16(pa, bv, acc[j], 0, 0, 0);
        }
      }
    }
    __syncthreads(); // all reads of Ks/Vs done
    if (kt + 1 < nkt) {
      commit();
      __syncthreads(); // staged tile visible
    }
  }
  float linv = 1.f / l_s;
  float lb[4];
#pragma unroll
  for (int r = 0; r < 4; r++) lb[r] = __shfl(linv, lk * 4 + r);
  size_t orow = (size_t)b * 2048 + qbw + lk * 4;
#pragma unroll
  for (int j = 0; j < 8; j++)
#pragma unroll
    for (int r = 0; r < 4; r++)
      O[(orow + r) * 2048 + h * 128 + j * 16 + lr] = (bf16_t)(acc[j][r] * lb[r]);
}

extern "C" void kernel_launch(void* const* d_in, const int* in_sizes, int n_in,
                              void* d_out, int out_size, void* d_ws, size_t ws_size,
                              hipStream_t stream) {
  const float* x = (const float*)d_in[0];
  const float* freqs = (const float*)d_in[1];
  const float* wq_a = (const float*)d_in[2];
  const float* q_norm_w = (const float*)d_in[3];
  const float* wq_b = (const float*)d_in[4];
  const float* wkv_a = (const float*)d_in[5];
  const float* kv_norm_w = (const float*)d_in[6];
  const float* wkv_b = (const float*)d_in[7];
  const float* wo = (const float*)d_in[8];
  float* out = (float*)d_out;
  char* ws = (char*)d_ws;

  // bf16 intermediates (first 64MB region): kvall, kvfull, q_a out
  bf16_t* kvallb = (bf16_t*)(ws);              // 4096x576
  bf16_t* kvfullb = (bf16_t*)(ws + 8388608);   // 4096x4096
  bf16_t* qab = (bf16_t*)(ws + 50331648);      // 4096x1536
  bf16_t* xbf = (bf16_t*)(ws + 67108864);
  bf16_t* wqab = (bf16_t*)(ws + 83886080);
  bf16_t* wqbb = (bf16_t*)(ws + 90177536);
  bf16_t* wkvab = (bf16_t*)(ws + 99614720);
  bf16_t* wkvbb = (bf16_t*)(ws + 101974016);
  bf16_t* wob = (bf16_t*)(ws + 106168320);
  bf16_t* qan = (bf16_t*)(ws + 114556928);
  bf16_t* kvn = (bf16_t*)(ws + 127139840);
  bf16_t* Qb = (bf16_t*)(ws + 131334144);
  bf16_t* Kb = (bf16_t*)(ws + 156499968);
  bf16_t* Vtb = (bf16_t*)(ws + 181665792);
  bf16_t* aob = (bf16_t*)(ws + 198443008);
  (void)in_sizes; (void)n_in; (void)out_size; (void)ws_size;

  auto cast = [&](const float* src, bf16_t* dst, int n) {
    int n8 = n / 8;
    k_cast_bf16<<<(n8 + 255) / 256, 256, 0, stream>>>(src, dst, n8);
  };
  cast(x, xbf, 8388608);
  cast(wq_a, wqab, 3145728);
  cast(wq_b, wqbb, 4718592);
  cast(wkv_a, wkvab, 1179648);
  cast(wkv_b, wkvbb, 2097152);
  cast(wo, wob, 4194304);

  // KV branch
  k_gemm_t<1><<<dim3(5, 32), 256, 0, stream>>>(xbf, wkvab, kvallb, 4096, 576, 2048, nullptr);
  k_kv_norm_rope<<<4096, 256, 0, stream>>>(kvallb, kv_norm_w, freqs, kvn, Kb);
  k_gemm_t<1><<<dim3(32, 32), 256, 0, stream>>>(kvn, wkvbb, kvfullb, 4096, 4096, 512, nullptr);
  k_split_kv<<<dim3(64, 16), 256, 0, stream>>>(kvfullb, Kb, Vtb);
  // Q branch
  k_gemm_t<1><<<dim3(12, 32), 256, 0, stream>>>(xbf, wqab, qab, 4096, 1536, 2048, nullptr);
  k_rms_q<<<4096, 256, 0, stream>>>(qab, q_norm_w, qan);
  k_gemm_t<2><<<dim3(24, 32), 256, 0, stream>>>(qan, wqbb, Qb, 4096, 3072, 1536, freqs);
  // Attention
  k_attn<<<dim3(16, 32), 512, 0, stream>>>(Qb, Kb, Vtb, aob);
  // Output projection -> d_out (fp32)
  k_gemm_t<0><<<dim3(16, 32), 256, 0, stream>>>(aob, wob, out, 4096, 2048, 2048, nullptr);
}

// Round 6
// 527.861 us; speedup vs baseline: 1.9734x; 1.0984x over previous
//
#include <hip/hip_runtime.h>

typedef __bf16 bf16_t;
typedef bf16_t bf16x8 __attribute__((ext_vector_type(8)));
typedef bf16_t bf16x4v __attribute__((ext_vector_type(4)));
typedef float f32x4 __attribute__((ext_vector_type(4)));

// B=2, S=2048, HID=2048, H=16, Q_LORA=1536, KV_LORA=512, D_NOPE=128, D_ROPE=64, D_V=128, D_QK=192
static constexpr float QSCALE = 0.07216878364870323f * 1.44269504088896341f; // 192^-0.5 * log2(e)

#define AS1 __attribute__((address_space(1)))
#define AS3 __attribute__((address_space(3)))
__device__ __forceinline__ void g2lds16(const void* g, void* l) {
  __builtin_amdgcn_global_load_lds((const AS1 void*)g, (AS3 void*)l, 16, 0, 0);
}

// ---------------- fused cast fp32 -> bf16, 6 segments in one launch ----------------
__global__ __launch_bounds__(256) void k_cast_all(
    const float* __restrict__ s0, const float* __restrict__ s1, const float* __restrict__ s2,
    const float* __restrict__ s3, const float* __restrict__ s4, const float* __restrict__ s5,
    bf16_t* __restrict__ d0, bf16_t* __restrict__ d1, bf16_t* __restrict__ d2,
    bf16_t* __restrict__ d3, bf16_t* __restrict__ d4, bf16_t* __restrict__ d5,
    int c1, int c2, int c3, int c4, int c5, int c6) {
  int g = blockIdx.x * 256 + threadIdx.x;
  const float* s; bf16_t* d; int off;
  if (g < c1) { s = s0; d = d0; off = 0; }
  else if (g < c2) { s = s1; d = d1; off = c1; }
  else if (g < c3) { s = s2; d = d2; off = c2; }
  else if (g < c4) { s = s3; d = d3; off = c3; }
  else if (g < c5) { s = s4; d = d4; off = c4; }
  else if (g < c6) { s = s5; d = d5; off = c5; }
  else return;
  int i = g - off;
  const float4* p = (const float4*)s + (size_t)i * 2;
  float4 a = p[0], b = p[1];
  bf16x8 o = {(bf16_t)a.x, (bf16_t)a.y, (bf16_t)a.z, (bf16_t)a.w,
              (bf16_t)b.x, (bf16_t)b.y, (bf16_t)b.z, (bf16_t)b.w};
  ((bf16x8*)d)[i] = o;
}

// ---------------- generic bf16 GEMM: C(MxN) = A(MxK) * Bt(NxK)^T ----------------
// 128x128 tile, BK=32, 4 waves. global_load_lds width=16 staging into linear [128][32].
// MODE 0: C fp32.  MODE 1: C bf16.  MODE 2: fused q rope+scale -> Qb [b*16+h][s][192].
// MODE 3: kv_b split: even 128-col tiles = k_nope -> aux (Kf layout); odd = V -> Cout compact.
template <int MODE>
__global__ __launch_bounds__(256) void k_gemm_t(
    const bf16_t* __restrict__ A, const bf16_t* __restrict__ Bt,
    void* __restrict__ Cout, int M, int N, int K, const float* __restrict__ freqs,
    bf16_t* __restrict__ aux) {
  __shared__ __align__(16) bf16_t As[128][32];
  __shared__ __align__(16) bf16_t Bs[128][32];
  const int tid = threadIdx.x;
  const int lane = tid & 63, wid = tid >> 6;
  const int wr = wid >> 1, wc = wid & 1;
  const int lr = lane & 15, lk = lane >> 4;
  const int bm = blockIdx.y * 128, bn = blockIdx.x * 128;
  f32x4 acc[4][4] = {};
  const int srow = wid * 16 + (lane >> 2);
  const int scol = (lane & 3) * 8;
  const bf16_t* a0 = A + (size_t)(bm + srow) * K + scol;
  const bf16_t* a1 = A + (size_t)(bm + 64 + srow) * K + scol;
  const bf16_t* b0 = Bt + (size_t)(bn + srow) * K + scol;       // OOB rows (ragged N) read
  const bf16_t* b1 = Bt + (size_t)(bn + 64 + srow) * K + scol;  // adjacent ws; masked at store
  bf16_t* lA0 = &As[wid * 16][0];
  bf16_t* lA1 = &As[64 + wid * 16][0];
  bf16_t* lB0 = &Bs[wid * 16][0];
  bf16_t* lB1 = &Bs[64 + wid * 16][0];
  for (int kt = 0; kt < K; kt += 32) {
    g2lds16(a0 + kt, lA0);
    g2lds16(a1 + kt, lA1);
    g2lds16(b0 + kt, lB0);
    g2lds16(b1 + kt, lB1);
    __syncthreads();
    bf16x8 af[4], bff[4];
#pragma unroll
    for (int i = 0; i < 4; i++)
      af[i] = *(const bf16x8*)(&As[wr * 64 + i * 16 + lr][lk * 8]);
#pragma unroll
    for (int j = 0; j < 4; j++)
      bff[j] = *(const bf16x8*)(&Bs[wc * 64 + j * 16 + lr][lk * 8]);
#pragma unroll
    for (int i = 0; i < 4; i++)
#pragma unroll
      for (int j = 0; j < 4; j++)
        acc[i][j] = __builtin_amdgcn_mfma_f32_16x16x32_bf16(af[i], bff[j], acc[i][j], 0, 0, 0);
    __syncthreads();
  }
  const int crow = bm + wr * 64 + lk * 4;
  const int ccol = bn + wc * 64 + lr;
#pragma unroll
  for (int i = 0; i < 4; i++)
#pragma unroll
    for (int j = 0; j < 4; j++) {
      int col = ccol + j * 16;
      if (col < N) {
        if constexpr (MODE == 0) {
          float* C = (float*)Cout;
#pragma unroll
          for (int r = 0; r < 4; r++)
            C[(size_t)(crow + i * 16 + r) * N + col] = acc[i][j][r];
        } else if constexpr (MODE == 1) {
          bf16_t* C = (bf16_t*)Cout;
#pragma unroll
          for (int r = 0; r < 4; r++)
            C[(size_t)(crow + i * 16 + r) * N + col] = (bf16_t)acc[i][j][r];
        } else if constexpr (MODE == 2) {
          // fused rope+scale epilogue -> Qb [b*16+h][s][192]
          bf16_t* Qd = (bf16_t*)Cout;
          int hcol = col / 192;
          int dmod = col - hcol * 192;
#pragma unroll
          for (int r = 0; r < 4; r++) {
            int row = crow + i * 16 + r;
            int bb = row >> 11, s = row & 2047;
            float v = acc[i][j][r];
            float partner = __shfl_xor(v, 1);
            if (dmod >= 128) {
              int pbase = ((lr & 1) == 0) ? (dmod - 128) : (dmod - 129);
              int p = pbase >> 1;
              float c = freqs[s * 64 + 2 * p];
              float sn = freqs[s * 64 + 2 * p + 1];
              v = ((lr & 1) == 0) ? (v * c - partner * sn) : (partner * sn + v * c);
            }
            Qd[((size_t)(bb * 16 + hcol) * 2048 + s) * 192 + dmod] = (bf16_t)(v * QSCALE);
          }
        } else {
          // MODE 3: kv_b. 128-col tiles alternate pure k_nope / pure V (256-wide heads).
          int h = bn >> 8;
          int d = col & 127;
          if ((bn & 128) == 0) {  // k_nope -> Kf [b*16+h][s][192]
#pragma unroll
            for (int r = 0; r < 4; r++) {
              int row = crow + i * 16 + r;
              int bb = row >> 11, s = row & 2047;
              aux[((size_t)(bb * 16 + h) * 2048 + s) * 192 + d] = (bf16_t)acc[i][j][r];
            }
          } else {  // V -> compact [row][h*128+d]
            bf16_t* C = (bf16_t*)Cout;
#pragma unroll
            for (int r = 0; r < 4; r++)
              C[(size_t)(crow + i * 16 + r) * 2048 + h * 128 + d] = (bf16_t)acc[i][j][r];
          }
        }
      }
    }
}

// ---------------- RMSNorm over 1536 (cols 0..1535 of [row][2112] bf16) -> bf16 ----------------
__global__ __launch_bounds__(256) void k_rms_q(const bf16_t* __restrict__ in,
                                               const float* __restrict__ w,
                                               bf16_t* __restrict__ out) {
  int row = blockIdx.x, tid = threadIdx.x;
  const bf16x8* x8 = (const bf16x8*)(in + (size_t)row * 2112);
  float ss = 0.f;
  bf16x8 v = {};
  if (tid < 192) {
    v = x8[tid];
#pragma unroll
    for (int j = 0; j < 8; j++) { float f = (float)v[j]; ss += f * f; }
  }
  for (int m = 32; m; m >>= 1) ss += __shfl_xor(ss, m);
  __shared__ float parts[4];
  if ((tid & 63) == 0) parts[tid >> 6] = ss;
  __syncthreads();
  float inv = rsqrtf((parts[0] + parts[1] + parts[2] + parts[3]) * (1.f / 1536.f) + 1e-6f);
  if (tid < 192) {
    const float4* w4 = (const float4*)(w + tid * 8);
    float4 w0 = w4[0], w1 = w4[1];
    bf16x8 o = {(bf16_t)((float)v[0] * inv * w0.x), (bf16_t)((float)v[1] * inv * w0.y),
                (bf16_t)((float)v[2] * inv * w0.z), (bf16_t)((float)v[3] * inv * w0.w),
                (bf16_t)((float)v[4] * inv * w1.x), (bf16_t)((float)v[5] * inv * w1.y),
                (bf16_t)((float)v[6] * inv * w1.z), (bf16_t)((float)v[7] * inv * w1.w)};
    *(bf16x8*)(out + (size_t)row * 1536 + tid * 8) = o;
  }
}

// ---------------- kv part (cols 1536..2111 of [row][2112]): RMSNorm(512)->kvn, rope->Kf ----------------
__global__ __launch_bounds__(256) void k_kv_norm_rope(const bf16_t* __restrict__ qkva,
                                                      const float* __restrict__ w,
                                                      const float* __restrict__ freqs,
                                                      bf16_t* __restrict__ kvn,
                                                      bf16_t* __restrict__ Kf) {
  int row = blockIdx.x, tid = threadIdx.x;
  int b = row >> 11, s = row & 2047;
  const bf16_t* x = qkva + (size_t)row * 2112 + 1536;
  float ss = 0.f;
  float vf[4] = {0.f, 0.f, 0.f, 0.f};
  if (tid < 128) {
    bf16x4v v4 = *(const bf16x4v*)(x + tid * 4);
#pragma unroll
    for (int j = 0; j < 4; j++) { vf[j] = (float)v4[j]; ss += vf[j] * vf[j]; }
  }
  for (int m = 32; m; m >>= 1) ss += __shfl_xor(ss, m);
  __shared__ float parts[4];
  if ((tid & 63) == 0) parts[tid >> 6] = ss;
  __syncthreads();
  float inv = rsqrtf((parts[0] + parts[1] + parts[2] + parts[3]) * (1.f / 512.f) + 1e-6f);
  if (tid < 128) {
    float4 ww = ((const float4*)w)[tid];
    bf16x4v o = {(bf16_t)(vf[0] * inv * ww.x), (bf16_t)(vf[1] * inv * ww.y),
                 (bf16_t)(vf[2] * inv * ww.z), (bf16_t)(vf[3] * inv * ww.w)};
    *(bf16x4v*)(kvn + (size_t)row * 512 + tid * 4) = o;
  }
  if (tid < 32) {
    float xr = (float)x[512 + 2 * tid], xi = (float)x[513 + 2 * tid];
    float c = freqs[s * 64 + 2 * tid], sn = freqs[s * 64 + 2 * tid + 1];
    bf16_t o0 = (bf16_t)(xr * c - xi * sn);
    bf16_t o1 = (bf16_t)(xr * sn + xi * c);
#pragma unroll
    for (int h = 0; h < 16; h++) {
      size_t base = ((size_t)(b * 16 + h) * 2048 + s) * 192 + 128 + 2 * tid;
      Kf[base] = o0;
      Kf[base + 1] = o1;
    }
  }
}

// ---------------- transpose compact V [row][h*128+d] -> Vt [b*16+h][d][s] ----------------
__global__ __launch_bounds__(256) void k_split_v(const bf16_t* __restrict__ Vc,
                                                 bf16_t* __restrict__ Vt) {
  __shared__ bf16_t vt_l[128][66];
  int s0 = blockIdx.x * 64;
  int h = blockIdx.y;
#pragma unroll 4
  for (int i = 0; i < 32; i++) {
    int idx = i * 256 + threadIdx.x;
    int r = idx >> 7, d = idx & 127;
    vt_l[d][r] = Vc[(size_t)(s0 + r) * 2048 + h * 128 + d];
  }
  __syncthreads();
#pragma unroll 4
  for (int i = 0; i < 32; i++) {
    int idx = i * 256 + threadIdx.x;
    int d = idx >> 6, ss = idx & 63;
    int row = s0 + ss;
    int b = row >> 11, s = row & 2047;
    Vt[((size_t)(b * 16 + h) * 128 + d) * 2048 + s] = vt_l[d][ss];
  }
}

// ---------------- flash attention v5: dbuf K/V via global_load_lds, prefetch-at-top ----------------
// Block: 512 thr = 8 waves x 16 q-rows (QBLK=128), KBLK=64, causal, heavy tiles first.
// Pipeline per tile: issue gload_lds prefetch of tile t+1 into buf^1, compute tile t from buf,
// one barrier (its vmcnt drain lands after the compute window -> latency hidden). XOR swizzles
// on K/V (pre-swizzled global source, linear LDS dest) and on P (verified bank math).
__global__ __launch_bounds__(512) void k_attn(const bf16_t* __restrict__ Q,
                                              const bf16_t* __restrict__ Kf,
                                              const bf16_t* __restrict__ Vt,
                                              bf16_t* __restrict__ O) {
  __shared__ __align__(16) bf16_t Ks[2][3][64][64];
  __shared__ __align__(16) bf16_t Vs[2][128][64];
  __shared__ __align__(16) bf16_t P[8][16][64];
  const int tid = threadIdx.x;
  const int lane = tid & 63, wid = tid >> 6;
  const int lr = lane & 15, lk = lane >> 4;
  const int r8 = lane >> 3, c8 = lane & 7;
  const int qt = (int)gridDim.x - 1 - (int)blockIdx.x; // heavy blocks dispatch first
  const int qb = qt * 128;
  const int qbw = qb + wid * 16;
  const int bh = blockIdx.y;
  const int b = bh >> 4, h = bh & 15;
  const bf16_t* Qp = Q + (size_t)bh * 2048 * 192;
  const bf16_t* Kb = Kf + (size_t)bh * 2048 * 192;
  const bf16_t* Vb = Vt + (size_t)bh * 128 * 2048;
  bf16x8 bq[6];
#pragma unroll
  for (int f = 0; f < 6; f++)
    bq[f] = *(const bf16x8*)(Qp + (size_t)(qbw + lr) * 192 + f * 32 + lk * 8);
  f32x4 acc[8] = {};
  float m_s = -1e30f, l_s = 0.f;
  const int q_mine = qbw + lr;
  // staging: 8 waves x (3 K-wavetiles + 2 V-wavetiles), each wavetile = 8 rows x 8 chunks x 16B
  auto stage = [&](int buf, int k0) {
#pragma unroll
    for (int t = 0; t < 3; t++) {
      int i = wid * 3 + t;           // 0..23
      int p = i >> 3, rb = i & 7;
      int row = rb * 8 + r8;
      g2lds16(Kb + (size_t)(k0 + row) * 192 + p * 64 + ((c8 ^ (row & 7)) * 8),
              &Ks[buf][p][row][c8 * 8]);
    }
#pragma unroll
    for (int t = 0; t < 2; t++) {
      int i = wid * 2 + t;           // 0..15
      int d = i * 8 + r8;
      g2lds16(Vb + (size_t)d * 2048 + k0 + ((c8 ^ (d & 7)) * 8), &Vs[buf][d][c8 * 8]);
    }
  };
  const int nkt = qt * 2 + 2;
  stage(0, 0);
  __syncthreads();
  int buf = 0;
  for (int kt = 0; kt < nkt; kt++) {
    const int k0 = kt * 64;
    if (kt + 1 < nkt) stage(buf ^ 1, k0 + 64); // prefetch in flight during compute
    if (k0 <= qbw + 15) {
      f32x4 sc[4];
#pragma unroll
      for (int hh = 0; hh < 4; hh++) {
        f32x4 a = {};
        const int row = hh * 16 + lr;
#pragma unroll
        for (int f = 0; f < 6; f++) {
          const int cc = (f & 1) * 4 + lk;
          bf16x8 ak = *(const bf16x8*)(&Ks[buf][f >> 1][row][((cc ^ (row & 7)) & 7) * 8]);
          a = __builtin_amdgcn_mfma_f32_16x16x32_bf16(ak, bq[f], a, 0, 0, 0);
        }
        sc[hh] = a;
      }
      if (k0 + 63 > qbw) {
#pragma unroll
        for (int hh = 0; hh < 4; hh++) {
          int key = k0 + hh * 16 + lk * 4;
#pragma unroll
          for (int r = 0; r < 4; r++)
            if (key + r > q_mine) sc[hh][r] = -1e30f;
        }
      }
      float t0 = fmaxf(fmaxf(sc[0][0], sc[0][1]), fmaxf(sc[0][2], sc[0][3]));
      float t1 = fmaxf(fmaxf(sc[1][0], sc[1][1]), fmaxf(sc[1][2], sc[1][3]));
      float t2 = fmaxf(fmaxf(sc[2][0], sc[2][1]), fmaxf(sc[2][2], sc[2][3]));
      float t3 = fmaxf(fmaxf(sc[3][0], sc[3][1]), fmaxf(sc[3][2], sc[3][3]));
      float tmax = fmaxf(fmaxf(t0, t1), fmaxf(t2, t3));
      tmax = fmaxf(tmax, __shfl_xor(tmax, 16));
      tmax = fmaxf(tmax, __shfl_xor(tmax, 32));
      float mn = fmaxf(m_s, tmax);
      float alpha = exp2f(m_s - mn);
      m_s = mn;
      float sm = 0.f;
#pragma unroll
      for (int hh = 0; hh < 4; hh++) {
#pragma unroll
        for (int r = 0; r < 4; r++) {
          float p = exp2f(sc[hh][r] - mn);
          sc[hh][r] = p;
          sm += p;
        }
      }
      sm += __shfl_xor(sm, 16);
      sm += __shfl_xor(sm, 32);
      l_s = l_s * alpha + sm;
      // P -> per-wave LDS, XOR-swizzled chunks (stride 64, chunk' = c ^ (lr&7))
#pragma unroll
      for (int hh = 0; hh < 4; hh++) {
        int c = hh * 2 + (lk >> 1);
        int coff = ((c ^ (lr & 7)) * 8) + (lk & 1) * 4;
        bf16x4v pv = {(bf16_t)sc[hh][0], (bf16_t)sc[hh][1], (bf16_t)sc[hh][2], (bf16_t)sc[hh][3]};
        *(bf16x4v*)(&P[wid][lr][coff]) = pv;
      }
      float ab[4];
#pragma unroll
      for (int r = 0; r < 4; r++) ab[r] = __shfl(alpha, lk * 4 + r);
#pragma unroll
      for (int j = 0; j < 8; j++)
#pragma unroll
        for (int r = 0; r < 4; r++) acc[j][r] *= ab[r];
#pragma unroll
      for (int s2 = 0; s2 < 2; s2++) {
        bf16x8 pa = *(const bf16x8*)(&P[wid][lr][((s2 * 4 + lk) ^ (lr & 7)) * 8]);
#pragma unroll
        for (int j = 0; j < 8; j++) {
          const int d = j * 16 + lr;
          bf16x8 bv = *(const bf16x8*)(&Vs[buf][d][((s2 * 4 + lk) ^ (d & 7)) * 8]);
          acc[j] = __builtin_amdgcn_mfma_f32_16x16x32_bf16(pa, bv, acc[j], 0, 0, 0);
        }
      }
    }
    __syncthreads(); // reads of buf done + prefetch into buf^1 drained
    buf ^= 1;
  }
  float linv = 1.f / l_s;
  float lb[4];
#pragma unroll
  for (int r = 0; r < 4; r++) lb[r] = __shfl(linv, lk * 4 + r);
  size_t orow = (size_t)b * 2048 + qbw + lk * 4;
#pragma unroll
  for (int j = 0; j < 8; j++)
#pragma unroll
    for (int r = 0; r < 4; r++)
      O[(orow + r) * 2048 + h * 128 + j * 16 + lr] = (bf16_t)(acc[j][r] * lb[r]);
}

extern "C" void kernel_launch(void* const* d_in, const int* in_sizes, int n_in,
                              void* d_out, int out_size, void* d_ws, size_t ws_size,
                              hipStream_t stream) {
  const float* x = (const float*)d_in[0];
  const float* freqs = (const float*)d_in[1];
  const float* wq_a = (const float*)d_in[2];
  const float* q_norm_w = (const float*)d_in[3];
  const float* wq_b = (const float*)d_in[4];
  const float* wkv_a = (const float*)d_in[5];
  const float* kv_norm_w = (const float*)d_in[6];
  const float* wkv_b = (const float*)d_in[7];
  const float* wo = (const float*)d_in[8];
  float* out = (float*)d_out;
  char* ws = (char*)d_ws;

  bf16_t* qkvab = (bf16_t*)(ws);               // 4096 x 2112 bf16 (q_a | kv_a merged)
  bf16_t* Vc = (bf16_t*)(ws + 25165824);       // 4096 x 2048 bf16 compact V
  bf16_t* xbf = (bf16_t*)(ws + 67108864);
  bf16_t* wqab = (bf16_t*)(ws + 83886080);     // 1536x2048
  bf16_t* wkvab = (bf16_t*)(ws + 90177536);    // 576x2048 (adjacent to wqab -> merged Bt)
  bf16_t* wqbb = (bf16_t*)(ws + 92536832);     // 3072x1536
  bf16_t* wkvbb = (bf16_t*)(ws + 101974016);   // 4096x512
  bf16_t* wob = (bf16_t*)(ws + 106168320);     // 2048x2048
  bf16_t* qan = (bf16_t*)(ws + 114556928);     // 4096x1536
  bf16_t* kvn = (bf16_t*)(ws + 127139840);     // 4096x512
  bf16_t* Qb = (bf16_t*)(ws + 131334144);      // 32x2048x192
  bf16_t* Kb = (bf16_t*)(ws + 156499968);      // 32x2048x192
  bf16_t* Vtb = (bf16_t*)(ws + 181665792);     // 32x128x2048
  bf16_t* aob = (bf16_t*)(ws + 198443008);     // 4096x2048
  (void)in_sizes; (void)n_in; (void)out_size; (void)ws_size;

  // all casts in one launch: x, wq_a, wkv_a, wq_b, wkv_b, wo
  {
    int n_x = 1048576, n_qa = 393216, n_kva = 147456, n_qb = 589824, n_kvb = 262144, n_o = 524288;
    int c1 = n_x, c2 = c1 + n_qa, c3 = c2 + n_kva, c4 = c3 + n_qb, c5 = c4 + n_kvb, c6 = c5 + n_o;
    k_cast_all<<<(c6 + 255) / 256, 256, 0, stream>>>(
        x, wq_a, wkv_a, wq_b, wkv_b, wo,
        xbf, wqab, wkvab, wqbb, wkvbb, wob,
        c1, c2, c3, c4, c5, c6);
  }

  // merged q_a + kv_a GEMM: [4096,2048] x [2112,2048]^T -> qkvab [4096][2112]
  k_gemm_t<1><<<dim3(17, 32), 256, 0, stream>>>(xbf, wqab, qkvab, 4096, 2112, 2048, nullptr, nullptr);
  k_kv_norm_rope<<<4096, 256, 0, stream>>>(qkvab, kv_norm_w, freqs, kvn, Kb);
  // kv_b GEMM with split epilogue: k_nope -> Kb direct, V -> Vc compact
  k_gemm_t<3><<<dim3(32, 32), 256, 0, stream>>>(kvn, wkvbb, Vc, 4096, 4096, 512, nullptr, Kb);
  k_split_v<<<dim3(64, 16), 256, 0, stream>>>(Vc, Vtb);
  // Q branch
  k_rms_q<<<4096, 256, 0, stream>>>(qkvab, q_norm_w, qan);
  k_gemm_t<2><<<dim3(24, 32), 256, 0, stream>>>(qan, wqbb, Qb, 4096, 3072, 1536, freqs, nullptr);
  // Attention
  k_attn<<<dim3(16, 32), 512, 0, stream>>>(Qb, Kb, Vtb, aob);
  // Output projection -> d_out (fp32)
  k_gemm_t<0><<<dim3(16, 32), 256, 0, stream>>>(aob, wob, out, 4096, 2048, 2048, nullptr, nullptr);
}

// Round 8
// 489.467 us; speedup vs baseline: 2.1282x; 1.0784x over previous
//
#include <hip/hip_runtime.h>

typedef __bf16 bf16_t;
typedef bf16_t bf16x8 __attribute__((ext_vector_type(8)));
typedef bf16_t bf16x4v __attribute__((ext_vector_type(4)));
typedef float f32x4 __attribute__((ext_vector_type(4)));
typedef float f32x16 __attribute__((ext_vector_type(16)));
typedef unsigned int u32;

// B=2, S=2048, HID=2048, H=16, Q_LORA=1536, KV_LORA=512, D_NOPE=128, D_ROPE=64, D_V=128, D_QK=192
static constexpr float QSCALE = 0.07216878364870323f * 1.44269504088896341f; // 192^-0.5 * log2(e)

#define AS1 __attribute__((address_space(1)))
#define AS3 __attribute__((address_space(3)))
__device__ __forceinline__ void g2lds16(const void* g, void* l) {
  __builtin_amdgcn_global_load_lds((const AS1 void*)g, (AS3 void*)l, 16, 0, 0);
}

__device__ __forceinline__ u32 pack2(float a, float b) {
  union { bf16_t h[2]; u32 u; } c;
  c.h[0] = (bf16_t)a; c.h[1] = (bf16_t)b;
  return c.u;
}

// ---------------- fused cast fp32 -> bf16, 6 segments in one launch ----------------
__global__ __launch_bounds__(256) void k_cast_all(
    const float* __restrict__ s0, const float* __restrict__ s1, const float* __restrict__ s2,
    const float* __restrict__ s3, const float* __restrict__ s4, const float* __restrict__ s5,
    bf16_t* __restrict__ d0, bf16_t* __restrict__ d1, bf16_t* __restrict__ d2,
    bf16_t* __restrict__ d3, bf16_t* __restrict__ d4, bf16_t* __restrict__ d5,
    int c1, int c2, int c3, int c4, int c5, int c6) {
  int g = blockIdx.x * 256 + threadIdx.x;
  const float* s; bf16_t* d; int off;
  if (g < c1) { s = s0; d = d0; off = 0; }
  else if (g < c2) { s = s1; d = d1; off = c1; }
  else if (g < c3) { s = s2; d = d2; off = c2; }
  else if (g < c4) { s = s3; d = d3; off = c3; }
  else if (g < c5) { s = s4; d = d4; off = c4; }
  else if (g < c6) { s = s5; d = d5; off = c5; }
  else return;
  int i = g - off;
  const float4* p = (const float4*)s + (size_t)i * 2;
  float4 a = p[0], b = p[1];
  bf16x8 o = {(bf16_t)a.x, (bf16_t)a.y, (bf16_t)a.z, (bf16_t)a.w,
              (bf16_t)b.x, (bf16_t)b.y, (bf16_t)b.z, (bf16_t)b.w};
  ((bf16x8*)d)[i] = o;
}

// ---------------- generic bf16 GEMM: C(MxN) = A(MxK) * Bt(NxK)^T ----------------
// 128x128 tile, BK=32, 4 waves. global_load_lds width=16 staging into linear [128][32].
// MODE 0: C fp32.  MODE 1: C bf16.  MODE 2: fused q rope+scale -> Qb [b*16+h][s][192].
// MODE 3: kv_b split: even 128-col tiles = k_nope -> aux (Kf layout); odd = V -> Cout compact.
template <int MODE>
__global__ __launch_bounds__(256) void k_gemm_t(
    const bf16_t* __restrict__ A, const bf16_t* __restrict__ Bt,
    void* __restrict__ Cout, int M, int N, int K, const float* __restrict__ freqs,
    bf16_t* __restrict__ aux) {
  __shared__ __align__(16) bf16_t As[128][32];
  __shared__ __align__(16) bf16_t Bs[128][32];
  const int tid = threadIdx.x;
  const int lane = tid & 63, wid = tid >> 6;
  const int wr = wid >> 1, wc = wid & 1;
  const int lr = lane & 15, lk = lane >> 4;
  const int bm = blockIdx.y * 128, bn = blockIdx.x * 128;
  f32x4 acc[4][4] = {};
  const int srow = wid * 16 + (lane >> 2);
  const int scol = (lane & 3) * 8;
  const bf16_t* a0 = A + (size_t)(bm + srow) * K + scol;
  const bf16_t* a1 = A + (size_t)(bm + 64 + srow) * K + scol;
  const bf16_t* b0 = Bt + (size_t)(bn + srow) * K + scol;
  const bf16_t* b1 = Bt + (size_t)(bn + 64 + srow) * K + scol;
  bf16_t* lA0 = &As[wid * 16][0];
  bf16_t* lA1 = &As[64 + wid * 16][0];
  bf16_t* lB0 = &Bs[wid * 16][0];
  bf16_t* lB1 = &Bs[64 + wid * 16][0];
  for (int kt = 0; kt < K; kt += 32) {
    g2lds16(a0 + kt, lA0);
    g2lds16(a1 + kt, lA1);
    g2lds16(b0 + kt, lB0);
    g2lds16(b1 + kt, lB1);
    __syncthreads();
    bf16x8 af[4], bff[4];
#pragma unroll
    for (int i = 0; i < 4; i++)
      af[i] = *(const bf16x8*)(&As[wr * 64 + i * 16 + lr][lk * 8]);
#pragma unroll
    for (int j = 0; j < 4; j++)
      bff[j] = *(const bf16x8*)(&Bs[wc * 64 + j * 16 + lr][lk * 8]);
#pragma unroll
    for (int i = 0; i < 4; i++)
#pragma unroll
      for (int j = 0; j < 4; j++)
        acc[i][j] = __builtin_amdgcn_mfma_f32_16x16x32_bf16(af[i], bff[j], acc[i][j], 0, 0, 0);
    __syncthreads();
  }
  const int crow = bm + wr * 64 + lk * 4;
  const int ccol = bn + wc * 64 + lr;
#pragma unroll
  for (int i = 0; i < 4; i++)
#pragma unroll
    for (int j = 0; j < 4; j++) {
      int col = ccol + j * 16;
      if (col < N) {
        if constexpr (MODE == 0) {
          float* C = (float*)Cout;
#pragma unroll
          for (int r = 0; r < 4; r++)
            C[(size_t)(crow + i * 16 + r) * N + col] = acc[i][j][r];
        } else if constexpr (MODE == 1) {
          bf16_t* C = (bf16_t*)Cout;
#pragma unroll
          for (int r = 0; r < 4; r++)
            C[(size_t)(crow + i * 16 + r) * N + col] = (bf16_t)acc[i][j][r];
        } else if constexpr (MODE == 2) {
          bf16_t* Qd = (bf16_t*)Cout;
          int hcol = col / 192;
          int dmod = col - hcol * 192;
#pragma unroll
          for (int r = 0; r < 4; r++) {
            int row = crow + i * 16 + r;
            int bb = row >> 11, s = row & 2047;
            float v = acc[i][j][r];
            float partner = __shfl_xor(v, 1);
            if (dmod >= 128) {
              int pbase = ((lr & 1) == 0) ? (dmod - 128) : (dmod - 129);
              int p = pbase >> 1;
              float c = freqs[s * 64 + 2 * p];
              float sn = freqs[s * 64 + 2 * p + 1];
              v = ((lr & 1) == 0) ? (v * c - partner * sn) : (partner * sn + v * c);
            }
            Qd[((size_t)(bb * 16 + hcol) * 2048 + s) * 192 + dmod] = (bf16_t)(v * QSCALE);
          }
        } else {
          int h = bn >> 8;
          int d = col & 127;
          if ((bn & 128) == 0) {
#pragma unroll
            for (int r = 0; r < 4; r++) {
              int row = crow + i * 16 + r;
              int bb = row >> 11, s = row & 2047;
              aux[((size_t)(bb * 16 + h) * 2048 + s) * 192 + d] = (bf16_t)acc[i][j][r];
            }
          } else {
            bf16_t* C = (bf16_t*)Cout;
#pragma unroll
            for (int r = 0; r < 4; r++)
              C[(size_t)(crow + i * 16 + r) * 2048 + h * 128 + d] = (bf16_t)acc[i][j][r];
          }
        }
      }
    }
}

// ---------------- RMSNorm over 1536 (cols 0..1535 of [row][2112] bf16) -> bf16 ----------------
__global__ __launch_bounds__(256) void k_rms_q(const bf16_t* __restrict__ in,
                                               const float* __restrict__ w,
                                               bf16_t* __restrict__ out) {
  int row = blockIdx.x, tid = threadIdx.x;
  const bf16x8* x8 = (const bf16x8*)(in + (size_t)row * 2112);
  float ss = 0.f;
  bf16x8 v = {};
  if (tid < 192) {
    v = x8[tid];
#pragma unroll
    for (int j = 0; j < 8; j++) { float f = (float)v[j]; ss += f * f; }
  }
  for (int m = 32; m; m >>= 1) ss += __shfl_xor(ss, m);
  __shared__ float parts[4];
  if ((tid & 63) == 0) parts[tid >> 6] = ss;
  __syncthreads();
  float inv = rsqrtf((parts[0] + parts[1] + parts[2] + parts[3]) * (1.f / 1536.f) + 1e-6f);
  if (tid < 192) {
    const float4* w4 = (const float4*)(w + tid * 8);
    float4 w0 = w4[0], w1 = w4[1];
    bf16x8 o = {(bf16_t)((float)v[0] * inv * w0.x), (bf16_t)((float)v[1] * inv * w0.y),
                (bf16_t)((float)v[2] * inv * w0.z), (bf16_t)((float)v[3] * inv * w0.w),
                (bf16_t)((float)v[4] * inv * w1.x), (bf16_t)((float)v[5] * inv * w1.y),
                (bf16_t)((float)v[6] * inv * w1.z), (bf16_t)((float)v[7] * inv * w1.w)};
    *(bf16x8*)(out + (size_t)row * 1536 + tid * 8) = o;
  }
}

// ---------------- kv part (cols 1536..2111 of [row][2112]): RMSNorm(512)->kvn, rope->Kf ----------------
__global__ __launch_bounds__(256) void k_kv_norm_rope(const bf16_t* __restrict__ qkva,
                                                      const float* __restrict__ w,
                                                      const float* __restrict__ freqs,
                                                      bf16_t* __restrict__ kvn,
                                                      bf16_t* __restrict__ Kf) {
  int row = blockIdx.x, tid = threadIdx.x;
  int b = row >> 11, s = row & 2047;
  const bf16_t* x = qkva + (size_t)row * 2112 + 1536;
  float ss = 0.f;
  float vf[4] = {0.f, 0.f, 0.f, 0.f};
  if (tid < 128) {
    bf16x4v v4 = *(const bf16x4v*)(x + tid * 4);
#pragma unroll
    for (int j = 0; j < 4; j++) { vf[j] = (float)v4[j]; ss += vf[j] * vf[j]; }
  }
  for (int m = 32; m; m >>= 1) ss += __shfl_xor(ss, m);
  __shared__ float parts[4];
  if ((tid & 63) == 0) parts[tid >> 6] = ss;
  __syncthreads();
  float inv = rsqrtf((parts[0] + parts[1] + parts[2] + parts[3]) * (1.f / 512.f) + 1e-6f);
  if (tid < 128) {
    float4 ww = ((const float4*)w)[tid];
    bf16x4v o = {(bf16_t)(vf[0] * inv * ww.x), (bf16_t)(vf[1] * inv * ww.y),
                 (bf16_t)(vf[2] * inv * ww.z), (bf16_t)(vf[3] * inv * ww.w)};
    *(bf16x4v*)(kvn + (size_t)row * 512 + tid * 4) = o;
  }
  if (tid < 32) {
    float xr = (float)x[512 + 2 * tid], xi = (float)x[513 + 2 * tid];
    float c = freqs[s * 64 + 2 * tid], sn = freqs[s * 64 + 2 * tid + 1];
    bf16_t o0 = (bf16_t)(xr * c - xi * sn);
    bf16_t o1 = (bf16_t)(xr * sn + xi * c);
#pragma unroll
    for (int h = 0; h < 16; h++) {
      size_t base = ((size_t)(b * 16 + h) * 2048 + s) * 192 + 128 + 2 * tid;
      Kf[base] = o0;
      Kf[base + 1] = o1;
    }
  }
}

// ---------------- transpose compact V [row][h*128+d] -> Vt [b*16+h][d][s] ----------------
__global__ __launch_bounds__(256) void k_split_v(const bf16_t* __restrict__ Vc,
                                                 bf16_t* __restrict__ Vt) {
  __shared__ bf16_t vt_l[128][66];
  int s0 = blockIdx.x * 64;
  int h = blockIdx.y;
#pragma unroll 4
  for (int i = 0; i < 32; i++) {
    int idx = i * 256 + threadIdx.x;
    int r = idx >> 7, d = idx & 127;
    vt_l[d][r] = Vc[(size_t)(s0 + r) * 2048 + h * 128 + d];
  }
  __syncthreads();
#pragma unroll 4
  for (int i = 0; i < 32; i++) {
    int idx = i * 256 + threadIdx.x;
    int d = idx >> 6, ss = idx & 63;
    int row = s0 + ss;
    int b = row >> 11, s = row & 2047;
    Vt[((size_t)(b * 16 + h) * 128 + d) * 2048 + s] = vt_l[d][ss];
  }
}

// ---------------- flash attention v6: 32x32 MFMA, 32 q/wave, lane-local softmax ----------------
// Block: 256 thr = 4 waves x 32 q (QBLK=128), KBLK=64, causal, heavy tiles first, dbuf LDS.
// Swapped QK: mfma_32x32x16(A=K, B=Q) -> S^T; lane owns q=lane&31, 32 keys in-register
// (rows (r&3)+8*(r>>2)+4*hi per group). Softmax lane-local + 1 shfl_xor(32).
// PV: O^T = mfma(A=V^T, B=P^T); P^T B-frags built in-register via pack + shfl_xor(32).
// 80KB LDS + <=256 VGPR -> 2 blocks/CU.
__global__ __launch_bounds__(256, 2) void k_attn(const bf16_t* __restrict__ Q,
                                                 const bf16_t* __restrict__ Kf,
                                                 const bf16_t* __restrict__ Vt,
                                                 bf16_t* __restrict__ O) {
  __shared__ __align__(16) bf16_t Ks[2][3][64][64];
  __shared__ __align__(16) bf16_t Vs[2][128][64];
  const int tid = threadIdx.x;
  const int lane = tid & 63, wid = tid >> 6;
  const int l31 = lane & 31, hi = lane >> 5;
  const int r8 = lane >> 3, c8 = lane & 7;
  const int qt = (int)gridDim.x - 1 - (int)blockIdx.x;
  const int qb = qt * 128;
  const int qbw = qb + wid * 32;
  const int bh = blockIdx.y;
  const int b = bh >> 4, h = bh & 15;
  const bf16_t* Qp = Q + (size_t)bh * 2048 * 192;
  const bf16_t* Kb = Kf + (size_t)bh * 2048 * 192;
  const bf16_t* Vb = Vt + (size_t)bh * 128 * 2048;
  const int q_mine = qbw + l31;
  // Q B-frags: col=q=lane&31, k=(lane>>5)*8+j -> Q[q][kk*16+hi*8+j]
  bf16x8 bq[12];
#pragma unroll
  for (int kk = 0; kk < 12; kk++)
    bq[kk] = *(const bf16x8*)(Qp + (size_t)q_mine * 192 + kk * 16 + hi * 8);
  f32x16 acc[4] = {};
  float m_s = -1e30f, l_s = 0.f;
  // staging: 40 wavetiles (24 K + 16 V), 4 waves x 10
  auto stage = [&](int buf, int k0) {
#pragma unroll
    for (int t = 0; t < 10; t++) {
      int i = t * 4 + wid;
      if (i < 24) {
        int p = i >> 3, rb = i & 7;
        int row = rb * 8 + r8;
        g2lds16(Kb + (size_t)(k0 + row) * 192 + p * 64 + ((c8 ^ (row & 7)) * 8),
                &Ks[buf][p][row][c8 * 8]);
      } else {
        int d = (i - 24) * 8 + r8;
        g2lds16(Vb + (size_t)d * 2048 + k0 + ((c8 ^ (d & 7)) * 8), &Vs[buf][d][c8 * 8]);
      }
    }
  };
  const int nkt = qt * 2 + 2;
  stage(0, 0);
  __syncthreads();
  int buf = 0;
  for (int kt = 0; kt < nkt; kt++) {
    const int k0 = kt * 64;
    if (kt + 1 < nkt) stage(buf ^ 1, k0 + 64);
    if (k0 <= qbw + 31) {
      // ---- QK^T: 2 key-groups x 12 k-steps ----
      f32x16 sg0 = {}, sg1 = {};
      const int rk0 = l31, rk1 = 32 + l31;
#pragma unroll
      for (int kk = 0; kk < 12; kk++) {
        int c = kk * 2 + hi;
        int p = c >> 3, cip = c & 7;
        bf16x8 ak0 = *(const bf16x8*)(&Ks[buf][p][rk0][(cip ^ (rk0 & 7)) * 8]);
        sg0 = __builtin_amdgcn_mfma_f32_32x32x16_bf16(ak0, bq[kk], sg0, 0, 0, 0);
        bf16x8 ak1 = *(const bf16x8*)(&Ks[buf][p][rk1][(cip ^ (rk1 & 7)) * 8]);
        sg1 = __builtin_amdgcn_mfma_f32_32x32x16_bf16(ak1, bq[kk], sg1, 0, 0, 0);
      }
      // ---- causal mask (diagonal region only) ----
      if (k0 + 63 > qbw) {
#pragma unroll
        for (int r = 0; r < 16; r++) {
          int ko = (r & 3) + 8 * (r >> 2) + 4 * hi;
          if (k0 + ko > q_mine) sg0[r] = -1e30f;
          if (k0 + 32 + ko > q_mine) sg1[r] = -1e30f;
        }
      }
      // ---- lane-local softmax (q = lane&31; partner lane^32 has same q) ----
      float tmax = -1e30f;
#pragma unroll
      for (int r = 0; r < 16; r++) tmax = fmaxf(tmax, fmaxf(sg0[r], sg1[r]));
      tmax = fmaxf(tmax, __shfl_xor(tmax, 32));
      bool defer = __all(tmax <= m_s + 8.0f);
      float mn = defer ? m_s : fmaxf(m_s, tmax);
      if (!defer) {
        float alpha = exp2f(m_s - mn);
        m_s = mn;
        l_s *= alpha;
#pragma unroll
        for (int jb = 0; jb < 4; jb++)
#pragma unroll
          for (int r = 0; r < 16; r++) acc[jb][r] *= alpha;
      }
      float sm = 0.f;
#pragma unroll
      for (int r = 0; r < 16; r++) {
        sg0[r] = exp2f(sg0[r] - mn);
        sg1[r] = exp2f(sg1[r] - mn);
        sm += sg0[r] + sg1[r];
      }
      sm += __shfl_xor(sm, 32);
      l_s += sm;
      // ---- pack P to bf16 pairs; partner exchange ----
      u32 pk0[8], pk1[8], pp0[8], pp1[8];
#pragma unroll
      for (int i = 0; i < 8; i++) {
        pk0[i] = pack2(sg0[2 * i], sg0[2 * i + 1]);
        pk1[i] = pack2(sg1[2 * i], sg1[2 * i + 1]);
        pp0[i] = __shfl_xor(pk0[i], 32);
        pp1[i] = __shfl_xor(pk1[i], 32);
      }
      // ---- PV: 4 k-steps of 16 keys; B-frag from pk/pp; A=V^T from LDS ----
#pragma unroll
      for (int s = 0; s < 4; s++) {
        const int par = s & 1;
        union { u32 u[4]; bf16x8 v; } fr;
        if (s < 2) {
          fr.u[0] = hi ? pp0[4 * par + 2] : pk0[4 * par + 0];
          fr.u[1] = hi ? pp0[4 * par + 3] : pk0[4 * par + 1];
          fr.u[2] = hi ? pk0[4 * par + 2] : pp0[4 * par + 0];
          fr.u[3] = hi ? pk0[4 * par + 3] : pp0[4 * par + 1];
        } else {
          fr.u[0] = hi ? pp1[4 * par + 2] : pk1[4 * par + 0];
          fr.u[1] = hi ? pp1[4 * par + 3] : pk1[4 * par + 1];
          fr.u[2] = hi ? pk1[4 * par + 2] : pp1[4 * par + 0];
          fr.u[3] = hi ? pk1[4 * par + 3] : pp1[4 * par + 1];
        }
        const int c = s * 2 + hi;
#pragma unroll
        for (int jb = 0; jb < 4; jb++) {
          const int d = jb * 32 + l31;
          bf16x8 av = *(const bf16x8*)(&Vs[buf][d][((c ^ (d & 7)) & 7) * 8]);
          acc[jb] = __builtin_amdgcn_mfma_f32_32x32x16_bf16(av, fr.v, acc[jb], 0, 0, 0);
        }
      }
    }
    __syncthreads();
    buf ^= 1;
  }
  // ---- epilogue: O^T[d][q] -> O[b*2048+q][h*128+d], l lane-local ----
  float linv = 1.f / l_s;
  bf16_t* orow = O + ((size_t)b * 2048 + q_mine) * 2048 + h * 128;
#pragma unroll
  for (int jb = 0; jb < 4; jb++)
#pragma unroll
    for (int k = 0; k < 4; k++) {
      int d0 = jb * 32 + 8 * k + 4 * hi;
      bf16x4v ov = {(bf16_t)(acc[jb][4 * k] * linv), (bf16_t)(acc[jb][4 * k + 1] * linv),
                    (bf16_t)(acc[jb][4 * k + 2] * linv), (bf16_t)(acc[jb][4 * k + 3] * linv)};
      *(bf16x4v*)(orow + d0) = ov;
    }
}

extern "C" void kernel_launch(void* const* d_in, const int* in_sizes, int n_in,
                              void* d_out, int out_size, void* d_ws, size_t ws_size,
                              hipStream_t stream) {
  const float* x = (const float*)d_in[0];
  const float* freqs = (const float*)d_in[1];
  const float* wq_a = (const float*)d_in[2];
  const float* q_norm_w = (const float*)d_in[3];
  const float* wq_b = (const float*)d_in[4];
  const float* wkv_a = (const float*)d_in[5];
  const float* kv_norm_w = (const float*)d_in[6];
  const float* wkv_b = (const float*)d_in[7];
  const float* wo = (const float*)d_in[8];
  float* out = (float*)d_out;
  char* ws = (char*)d_ws;

  bf16_t* qkvab = (bf16_t*)(ws);               // 4096 x 2112 bf16 (q_a | kv_a merged)
  bf16_t* Vc = (bf16_t*)(ws + 25165824);       // 4096 x 2048 bf16 compact V
  bf16_t* xbf = (bf16_t*)(ws + 67108864);
  bf16_t* wqab = (bf16_t*)(ws + 83886080);     // 1536x2048
  bf16_t* wkvab = (bf16_t*)(ws + 90177536);    // 576x2048 (adjacent to wqab -> merged Bt)
  bf16_t* wqbb = (bf16_t*)(ws + 92536832);     // 3072x1536
  bf16_t* wkvbb = (bf16_t*)(ws + 101974016);   // 4096x512
  bf16_t* wob = (bf16_t*)(ws + 106168320);     // 2048x2048
  bf16_t* qan = (bf16_t*)(ws + 114556928);     // 4096x1536
  bf16_t* kvn = (bf16_t*)(ws + 127139840);     // 4096x512
  bf16_t* Qb = (bf16_t*)(ws + 131334144);      // 32x2048x192
  bf16_t* Kb = (bf16_t*)(ws + 156499968);      // 32x2048x192
  bf16_t* Vtb = (bf16_t*)(ws + 181665792);     // 32x128x2048
  bf16_t* aob = (bf16_t*)(ws + 198443008);     // 4096x2048
  (void)in_sizes; (void)n_in; (void)out_size; (void)ws_size;

  {
    int n_x = 1048576, n_qa = 393216, n_kva = 147456, n_qb = 589824, n_kvb = 262144, n_o = 524288;
    int c1 = n_x, c2 = c1 + n_qa, c3 = c2 + n_kva, c4 = c3 + n_qb, c5 = c4 + n_kvb, c6 = c5 + n_o;
    k_cast_all<<<(c6 + 255) / 256, 256, 0, stream>>>(
        x, wq_a, wkv_a, wq_b, wkv_b, wo,
        xbf, wqab, wkvab, wqbb, wkvbb, wob,
        c1, c2, c3, c4, c5, c6);
  }

  // merged q_a + kv_a GEMM
  k_gemm_t<1><<<dim3(17, 32), 256, 0, stream>>>(xbf, wqab, qkvab, 4096, 2112, 2048, nullptr, nullptr);
  k_kv_norm_rope<<<4096, 256, 0, stream>>>(qkvab, kv_norm_w, freqs, kvn, Kb);
  // kv_b GEMM with split epilogue: k_nope -> Kb direct, V -> Vc compact
  k_gemm_t<3><<<dim3(32, 32), 256, 0, stream>>>(kvn, wkvbb, Vc, 4096, 4096, 512, nullptr, Kb);
  k_split_v<<<dim3(64, 16), 256, 0, stream>>>(Vc, Vtb);
  // Q branch
  k_rms_q<<<4096, 256, 0, stream>>>(qkvab, q_norm_w, qan);
  k_gemm_t<2><<<dim3(24, 32), 256, 0, stream>>>(qan, wqbb, Qb, 4096, 3072, 1536, freqs, nullptr);
  // Attention
  k_attn<<<dim3(16, 32), 256, 0, stream>>>(Qb, Kb, Vtb, aob);
  // Output projection -> d_out (fp32)
  k_gemm_t<0><<<dim3(16, 32), 256, 0, stream>>>(aob, wob, out, 4096, 2048, 2048, nullptr, nullptr);
}